// Round 9
// baseline (747.922 us; speedup 1.0000x reference)
//
#include <hip/hip_runtime.h>
#include <hip/hip_bf16.h>
#include <hip/hip_cooperative_groups.h>

typedef unsigned int u32;
typedef unsigned short u16;
typedef unsigned long long u64;

typedef __attribute__((ext_vector_type(8))) short bf16x8;
typedef __attribute__((ext_vector_type(4))) float f32x4;
typedef __attribute__((ext_vector_type(2))) float f32x2;

#define BCAP 1536  // edge capacity per 64-node bucket (mean 1024, sigma 32 -> 16-sigma headroom)

// bf16 = top 16 bits of fp32; RNE pack
static __device__ __forceinline__ float bflo(u32 u) { return __uint_as_float(u << 16); }
static __device__ __forceinline__ float bfhi(u32 u) { return __uint_as_float(u & 0xFFFF0000u); }
static __device__ __forceinline__ float bf2f(u16 u) { return __uint_as_float((u32)u << 16); }
static __device__ __forceinline__ u32 f2bf(float f) {
    u32 u = __float_as_uint(f);
    return (u + 0x7FFFu + ((u >> 16) & 1u)) >> 16;
}
static __device__ __forceinline__ u32 packbf(float lo, float hi) {
    return f2bf(lo) | (f2bf(hi) << 16);
}
static __device__ __forceinline__ float ldf(const u16* p16, int idx, int isf32) {
    return isf32 ? ((const float*)p16)[idx] : bf2f(p16[idx]);
}
// load 4 consecutive attention-vector elements [4*q .. 4*q+3]
static __device__ __forceinline__ void load4(const u16* p, int q, int isf32, float* v) {
    if (isf32) {
        float4 t = ((const float4*)p)[q];
        v[0] = t.x; v[1] = t.y; v[2] = t.z; v[3] = t.w;
    } else {
        u32 a = ((const u32*)p)[q * 2], b = ((const u32*)p)[q * 2 + 1];
        v[0] = bflo(a); v[1] = bfhi(a); v[2] = bflo(b); v[3] = bfhi(b);
    }
}
static __device__ __forceinline__ float sanitize(float v, float code) {
    return (fabsf(v) < 1e30f) ? v : code;
}

// unpack u32 (bf16 L | bf16 H<<16) into {L, H} fp32 pair
static __device__ __forceinline__ f32x2 up2(u32 u) {
    f32x2 r;
    r.x = __uint_as_float(u << 16);
    r.y = __uint_as_float(u & 0xFFFF0000u);
    return r;
}
// packed-pair fp32 FMA / ADD (VOP3P) — one instruction for both (L,H) planes
static __device__ __forceinline__ void pk_fma(f32x2& d, f32x2 a, f32x2 b) {
    asm("v_pk_fma_f32 %0, %1, %2, %0" : "+v"(d) : "v"(a), "v"(b));
}
static __device__ __forceinline__ void pk_add(f32x2& d, f32x2 a) {
    asm("v_pk_add_f32 %0, %1, %0" : "+v"(d) : "v"(a));
}

static __device__ __forceinline__ float wave_sum(float v) {
#pragma unroll
    for (int o = 32; o; o >>= 1) v += __shfl_xor(v, o, 64);
    return v;
}
// sum within 16-lane group (lanes grouped by lane>>4)
static __device__ __forceinline__ float group_sum(float v) {
#pragma unroll
    for (int o = 8; o; o >>= 1) v += __shfl_xor(v, o, 64);
    return v;
}

// ---------------- diagnostics / utility ----------------

__global__ void k_sentinel(float* __restrict__ out, int n, float val) {
    int i = blockIdx.x * blockDim.x + threadIdx.x;
    if (i < n) out[i] = val;
}

// dtype sniff over first 64x64 values of x (run by one 64-lane wave; result for lane 0)
static __device__ __forceinline__ int dev_sniff(const u16* x, int lane) {
    int wild = 0;
    for (int k = 0; k < 64; k++) {
        u32 u = x[lane * 64 + k];
        int e = (u >> 7) & 0xFF;
        if (e < 96 || e > 135) wild++;
    }
    float tot = wave_sum((float)wild);
    return (tot > 200.f) ? 1 : 0;
}

// pack W_low/W_high/W_mlp into MFMA fragment order (256 threads cooperate)
static __device__ void dev_prepB(const u16* wl, const u16* wh, const u16* wm, u16* Bpack,
                                 int isf32, int t) {
    for (int idx = t; idx < 12 * 2 * 64; idx += 256) {
        int slot = idx >> 6;
        int ln = idx & 63;
        int ct = slot >> 1, c = slot & 1;
        int mat = ct >> 2;
        const u16* W = (mat == 0) ? wl : (mat == 1) ? wh : wm;
        int col = (ct & 3) * 16 + (ln & 15);
        int kbase = c * 32 + (ln >> 4) * 8;
        u16* dst = Bpack + (size_t)idx * 8;
#pragma unroll
        for (int j = 0; j < 8; j++)
            dst[j] = (u16)f2bf(ldf(W, (kbase + j) * 64 + col, isf32));
    }
}

// scat1 body for one edge index i. Bucket = 64 consecutive dst nodes, capacity BCAP.
// dloc (6 bits) in payload bits 22..27, fake in 20..21, src in 0..19.
static __device__ __forceinline__ void dev_scat1_edge(
    int i, const int* src, const int* dst, const u16* avl, const u16* avh, const int* lab,
    int* bcur, u64* etmp, int isf32) {
    int d = dst[i];
    int b = d >> 6;
    int base = b << 6;
    int rank = atomicAdd(&bcur[b * 16], 1);  // counters padded to own 64B line
    if (rank >= BCAP) return;                // statistically impossible (16 sigma)
    int s = src[i];
    int sl = lab[s], dl = lab[d];
    int fake = (sl < 0 || dl < 0) ? 2 : ((sl != dl) ? 1 : 0);
    u32 lo32 = (u32)s | ((u32)fake << 20) | ((u32)(d - base) << 22);
    u32 hi32 = isf32 ? packbf(((const float*)avl)[i], ((const float*)avh)[i])
                     : ((u32)avl[i] | ((u32)avh[i] << 16));
    etmp[(size_t)b * BCAP + rank] = ((u64)hi32 << 32) | lo32;
}

// gemm body: waves [wv0, ...) stride nw over 16-row tiles; 24 MFMAs per tile
static __device__ void dev_gemm(const u16* x, const u16* Bpack, int N, u32* xwlh,
                                float* omlp, int isf32, int tid, int wv, int nw) {
    int lane = tid & 63;
    int m = lane & 15, quad = lane >> 4;
    int ntiles = (N + 15) >> 4;
    for (int tile = wv; tile < ntiles; tile += nw) {
        int r0 = tile * 16;
        int arow = min(r0 + m, N - 1);
        bf16x8 a[2];
#pragma unroll
        for (int c = 0; c < 2; c++) {
            int base = arow * 64 + c * 32 + quad * 8;
            if (isf32) {
                const float4* xf = (const float4*)x;
                int q = (base >> 2);
                float4 t0 = xf[q], t1 = xf[q + 1];
                a[c][0] = (short)f2bf(t0.x); a[c][1] = (short)f2bf(t0.y);
                a[c][2] = (short)f2bf(t0.z); a[c][3] = (short)f2bf(t0.w);
                a[c][4] = (short)f2bf(t1.x); a[c][5] = (short)f2bf(t1.y);
                a[c][6] = (short)f2bf(t1.z); a[c][7] = (short)f2bf(t1.w);
            } else {
                a[c] = *(const bf16x8*)(x + base);
            }
        }
        f32x4 acc[12];
#pragma unroll
        for (int t = 0; t < 12; t++) acc[t] = (f32x4){0.f, 0.f, 0.f, 0.f};
#pragma unroll
        for (int t = 0; t < 12; t++) {
#pragma unroll
            for (int c = 0; c < 2; c++) {
                bf16x8 b = *(const bf16x8*)(Bpack + (size_t)((t * 2 + c) * 64 + lane) * 8);
                acc[t] = __builtin_amdgcn_mfma_f32_16x16x32_bf16(a[c], b, acc[t], 0, 0, 0);
            }
        }
        // C/D: col = lane&15, row = quad*4 + reg
#pragma unroll
        for (int t = 0; t < 4; t++) {
#pragma unroll
            for (int r = 0; r < 4; r++) {
                int row = r0 + quad * 4 + r;
                if (row < N) {
                    int o = row * 64 + t * 16 + m;
                    xwlh[o] = packbf(acc[t][r], acc[t + 4][r]);
                    omlp[o] = fmaxf(acc[t + 8][r], 0.f);
                }
            }
        }
    }
}

// scat2+spmm for one 64-node bucket (block-cooperative; uses provided LDS arrays).
// Phase A: load edges to regs + count per (dloc, fake). Prefix -> per-node category
// boundaries (cb4 int4 = s|c1|c2|e). Phase B: place category-sorted into LDS stash +
// epay_lo. Phase C: spmm (payloads from stash, unroll-4, full 256B row gathers).
static __device__ void dev_bucket(
    int b, const u64* etmp, const int* bcur, int N, int4* cb4, u32* epay_lo,
    const u32* xwlh, u32* outlh, int t,
    int* cnt, int* startp, int* cur, int* tot, u64* stash) {
    int base = b << 6;
    int ebase = b * BCAP;
    if (t < 192) cnt[t] = 0;
    __syncthreads();
    int cntE = min(bcur[b * 16], BCAP);
    u64 ph[6];  // BCAP/256 = 6 max edges per thread
#pragma unroll
    for (int j = 0; j < 6; j++) {
        int e = t + j * 256;
        if (e < cntE) {
            u64 p = etmp[(size_t)ebase + e];
            ph[j] = p;
            int dl3 = ((int)(p >> 22) & 63) * 3 + ((int)(p >> 20) & 3);
            atomicAdd(&cnt[dl3], 1);
        }
    }
    __syncthreads();
    if (t < 64) tot[t] = cnt[t * 3] + cnt[t * 3 + 1] + cnt[t * 3 + 2];
    __syncthreads();
    for (int d = 1; d < 64; d <<= 1) {
        int v = 0;
        if (t < 64 && t >= d) v = tot[t - d];
        __syncthreads();
        if (t < 64) tot[t] += v;
        __syncthreads();
    }
    if (t < 64) {
        int c0 = cnt[t * 3], c1 = cnt[t * 3 + 1], c2 = cnt[t * 3 + 2];
        int own = c0 + c1 + c2;
        int ex = tot[t] - own;
        int s0 = ex, s1 = ex + c0, s2 = ex + c0 + c1;
        startp[t * 3] = s0;
        startp[t * 3 + 1] = s1;
        startp[t * 3 + 2] = s2;
        cur[t * 3] = s0;
        cur[t * 3 + 1] = s1;
        cur[t * 3 + 2] = s2;
        int node = base + t;
        if (node < N) {
            int4 cb;
            cb.x = ebase + s0;
            cb.y = ebase + s1;
            cb.z = ebase + s2;
            cb.w = ebase + ex + own;
            cb4[node] = cb;
        }
    }
    __syncthreads();
#pragma unroll
    for (int j = 0; j < 6; j++) {
        int e = t + j * 256;
        if (e < cntE) {
            u64 p = ph[j];
            int dl3 = ((int)(p >> 22) & 63) * 3 + ((int)(p >> 20) & 3);
            int rank = atomicAdd(&cur[dl3], 1);
            stash[rank] = p;
            epay_lo[(size_t)ebase + rank] = (u32)p;
        }
    }
    __syncthreads();
    // spmm: 16 feature-lanes x 16 groups, unroll-4 (4 gathers in flight)
    int g = t & 15, grp = t >> 4;
    const uint4* tab = (const uint4*)xwlh + g;
#pragma unroll
    for (int it = 0; it < 4; it++) {
        int dloc = it * 16 + grp;
        int node = base + dloc;
        if (node >= N) continue;
        int sR = startp[dloc * 3];
        int eR = startp[dloc * 3 + 2] + cnt[dloc * 3 + 2];
        f32x2 acc[4];
#pragma unroll
        for (int k = 0; k < 4; k++) acc[k] = (f32x2){0.f, 0.f};
        int idx = sR;
        for (; idx + 3 < eR; idx += 4) {
            u64 p0 = stash[idx], p1 = stash[idx + 1], p2 = stash[idx + 2], p3 = stash[idx + 3];
            uint4 R0 = tab[(size_t)(p0 & 0xFFFFF) << 4];
            uint4 R1 = tab[(size_t)(p1 & 0xFFFFF) << 4];
            uint4 R2 = tab[(size_t)(p2 & 0xFFFFF) << 4];
            uint4 R3 = tab[(size_t)(p3 & 0xFFFFF) << 4];
            f32x2 w0 = up2((u32)(p0 >> 32)), w1 = up2((u32)(p1 >> 32));
            f32x2 w2 = up2((u32)(p2 >> 32)), w3 = up2((u32)(p3 >> 32));
            pk_fma(acc[0], up2(R0.x), w0);
            pk_fma(acc[1], up2(R0.y), w0);
            pk_fma(acc[2], up2(R0.z), w0);
            pk_fma(acc[3], up2(R0.w), w0);
            pk_fma(acc[0], up2(R1.x), w1);
            pk_fma(acc[1], up2(R1.y), w1);
            pk_fma(acc[2], up2(R1.z), w1);
            pk_fma(acc[3], up2(R1.w), w1);
            pk_fma(acc[0], up2(R2.x), w2);
            pk_fma(acc[1], up2(R2.y), w2);
            pk_fma(acc[2], up2(R2.z), w2);
            pk_fma(acc[3], up2(R2.w), w2);
            pk_fma(acc[0], up2(R3.x), w3);
            pk_fma(acc[1], up2(R3.y), w3);
            pk_fma(acc[2], up2(R3.z), w3);
            pk_fma(acc[3], up2(R3.w), w3);
        }
        for (; idx < eR; idx++) {
            u64 p0 = stash[idx];
            uint4 R0 = tab[(size_t)(p0 & 0xFFFFF) << 4];
            f32x2 w0 = up2((u32)(p0 >> 32));
            pk_fma(acc[0], up2(R0.x), w0);
            pk_fma(acc[1], up2(R0.y), w0);
            pk_fma(acc[2], up2(R0.z), w0);
            pk_fma(acc[3], up2(R0.w), w0);
        }
        uint4 W;
        W.x = packbf(fmaxf(acc[0].x, 0.f), fmaxf(acc[0].y, 0.f));
        W.y = packbf(fmaxf(acc[1].x, 0.f), fmaxf(acc[1].y, 0.f));
        W.z = packbf(fmaxf(acc[2].x, 0.f), fmaxf(acc[2].y, 0.f));
        W.w = packbf(fmaxf(acc[3].x, 0.f), fmaxf(acc[3].y, 0.f));
        ((uint4*)(outlh + (size_t)node * 64))[g] = W;
    }
    __syncthreads();  // protect LDS before next bucket iteration
}

// agg body for one group-of-4-nodes wave set (prefix-snapshot over category-sorted
// segments: one long unroll-4 sweep, snapshot at c1/c2; He=S2-S1, Un=T-S2).
static __device__ void dev_agg_group(
    int gwave, const u32* outlh, const u32* epay_lo, const int4* cb4,
    const u16* aLF, const u16* aHF, const u16* aLB, const u16* aHB,
    const u16* aLU, const u16* aHU, const u16* aM, const u16* a7, int N,
    float* out, int isf32, int tid) {
    int lane = tid & 63;
    int g = lane & 15, gi = lane >> 4;
    int node = gwave * 4 + gi;
    bool vn = node < N;
    int4 cb = vn ? cb4[node] : (int4){0, 0, 0, 0};
    int s = cb.x, c1 = cb.y, c2 = cb.z, e = cb.w;
    const uint4* tab = (const uint4*)outlh + g;
    f32x2 acc[4], S1[4], S2[4];
#pragma unroll
    for (int k = 0; k < 4; k++) {
        acc[k] = (f32x2){0.f, 0.f};
        S1[k] = (f32x2){0.f, 0.f};
        S2[k] = (f32x2){0.f, 0.f};
    }
#define AGG_EDGE(R)                    \
    pk_add(acc[0], up2(R.x));          \
    pk_add(acc[1], up2(R.y));          \
    pk_add(acc[2], up2(R.z));          \
    pk_add(acc[3], up2(R.w));
#define AGG_CHK(q)                                                        \
    if ((q) == c1) { S1[0] = acc[0]; S1[1] = acc[1]; S1[2] = acc[2]; S1[3] = acc[3]; } \
    if ((q) == c2) { S2[0] = acc[0]; S2[1] = acc[1]; S2[2] = acc[2]; S2[3] = acc[3]; }
    int tt = s;
    for (; tt + 3 < e; tt += 4) {
        u32 p0 = epay_lo[tt], p1 = epay_lo[tt + 1];
        u32 p2 = epay_lo[tt + 2], p3 = epay_lo[tt + 3];
        uint4 R0 = tab[(size_t)(p0 & 0xFFFFF) << 4];
        uint4 R1 = tab[(size_t)(p1 & 0xFFFFF) << 4];
        uint4 R2 = tab[(size_t)(p2 & 0xFFFFF) << 4];
        uint4 R3 = tab[(size_t)(p3 & 0xFFFFF) << 4];
        AGG_EDGE(R0); AGG_CHK(tt + 1);
        AGG_EDGE(R1); AGG_CHK(tt + 2);
        AGG_EDGE(R2); AGG_CHK(tt + 3);
        AGG_EDGE(R3); AGG_CHK(tt + 4);
    }
    for (; tt < e; tt++) {
        u32 p0 = epay_lo[tt];
        uint4 R0 = tab[(size_t)(p0 & 0xFFFFF) << 4];
        AGG_EDGE(R0); AGG_CHK(tt + 1);
    }
#undef AGG_EDGE
#undef AGG_CHK
    float heL[4], heH[4], hoL[4], hoH[4], unL[4], unH[4];
#pragma unroll
    for (int k = 0; k < 4; k++) {
        hoL[k] = S1[k].x;            hoH[k] = S1[k].y;
        heL[k] = S2[k].x - S1[k].x;  heH[k] = S2[k].y - S1[k].y;
        unL[k] = acc[k].x - S2[k].x; unH[k] = acc[k].y - S2[k].y;
    }
    float vLF[4], vHF[4], vLB[4], vHB[4], vLU[4], vHU[4], vM[4];
    load4(aLF, g, isf32, vLF);
    load4(aHF, g, isf32, vHF);
    load4(aLB, g, isf32, vLB);
    load4(aHB, g, isf32, vHB);
    load4(aLU, g, isf32, vLU);
    load4(aHU, g, isf32, vHU);
    load4(aM, g, isf32, vM);
    float mvv[4] = {0.f, 0.f, 0.f, 0.f};
    if (vn) {
        float4 MV = ((const float4*)(out + (size_t)node * 64))[g];  // omlp staged in d_out
        mvv[0] = MV.x; mvv[1] = MV.y; mvv[2] = MV.z; mvv[3] = MV.w;
    }
    float p0 = 0, p1 = 0, p2 = 0, p3 = 0, p4 = 0, p5 = 0, p6 = 0;
#pragma unroll
    for (int k = 0; k < 4; k++) {
        p0 += heL[k] * vLF[k];
        p1 += heH[k] * vHF[k];
        p2 += hoL[k] * vLB[k];
        p3 += hoH[k] * vHB[k];
        p4 += unL[k] * vLU[k];
        p5 += unH[k] * vHU[k];
        p6 += mvv[k] * vM[k];
    }
    float d0 = group_sum(p0), d1 = group_sum(p1), d2 = group_sum(p2), d3 = group_sum(p3);
    float d4 = group_sum(p4), d5 = group_sum(p5), d6 = group_sum(p6);

    float f[7];
    f[0] = 1.f / (1.f + expf(-d0));
    f[1] = 1.f / (1.f + expf(-d1));
    f[2] = 1.f / (1.f + expf(-d2));
    f[3] = 1.f / (1.f + expf(-d3));
    f[4] = 1.f / (1.f + expf(-d4));
    f[5] = 1.f / (1.f + expf(-d5));
    f[6] = 1.f / (1.f + expf(-d6));

    float z[7];
#pragma unroll
    for (int jj = 0; jj < 7; jj++) {
        float acc7 = 0.f;
#pragma unroll
        for (int i = 0; i < 7; i++) acc7 += f[i] * ldf(a7, i * 7 + jj, isf32);
        z[jj] = acc7 * (1.f / 7.f);
    }
    float m = z[0];
#pragma unroll
    for (int jj = 1; jj < 7; jj++) m = fmaxf(m, z[jj]);
    float wsum = 0.f;
    float wv[7];
#pragma unroll
    for (int jj = 0; jj < 7; jj++) { wv[jj] = expf(z[jj] - m); wsum += wv[jj]; }
    float s7 = 7.f / wsum;

    if (vn) {
        float4 W;
        float o0 = wv[0] * heL[0] + wv[1] * heH[0] + wv[2] * hoL[0] + wv[3] * hoH[0] +
                   wv[4] * unL[0] + wv[5] * unH[0] + wv[6] * mvv[0];
        float o1 = wv[0] * heL[1] + wv[1] * heH[1] + wv[2] * hoL[1] + wv[3] * hoH[1] +
                   wv[4] * unL[1] + wv[5] * unH[1] + wv[6] * mvv[1];
        float o2 = wv[0] * heL[2] + wv[1] * heH[2] + wv[2] * hoL[2] + wv[3] * hoH[2] +
                   wv[4] * unL[2] + wv[5] * unH[2] + wv[6] * mvv[2];
        float o3 = wv[0] * heL[3] + wv[1] * heH[3] + wv[2] * hoL[3] + wv[3] * hoH[3] +
                   wv[4] * unL[3] + wv[5] * unH[3] + wv[6] * mvv[3];
        W.x = sanitize(o0 * s7, 333.f);
        W.y = sanitize(o1 * s7, 333.f);
        W.z = sanitize(o2 * s7, 333.f);
        W.w = sanitize(o3 * s7, 333.f);
        ((float4*)(out + (size_t)node * 64))[g] = W;
    }
}

// ---------------- cooperative mega-kernel: all 5 phases, 1 launch ----------------
// Phases kept SEQUENTIAL via grid.sync() (R5 lesson: scat1's L2-frontier scatter must
// not co-run with gemm's streaming writes). Grid sized by occupancy query (<= resident).
__launch_bounds__(256, 4) __global__
void k_mega(const u16* x, const u16* avl, const u16* avh,
            const u16* wl, const u16* wh, const u16* wm,
            const u16* aLF, const u16* aHF, const u16* aLB, const u16* aHB,
            const u16* aLU, const u16* aHU, const u16* aM, const u16* a7,
            const int* esrc, const int* edst, const int* lab,
            int N, int E, int NB2,
            int* flag, int* bcur, u16* Bpack, int4* cb4,
            u64* etmp, u32* epay_lo, u32* xwlh, u32* outlh, float* out) {
    __shared__ int cnt[192], startp[192], cur[192], tot[64];
    __shared__ u64 stash[BCAP];
    __shared__ int sflag;
    cooperative_groups::grid_group grid = cooperative_groups::this_grid();
    int t = threadIdx.x;
    int nblk = (int)gridDim.x;

    // ---- phase 0: zero bucket cursors + sniff + prepB ----
    for (int i = blockIdx.x * 256 + t; i < NB2 * 16; i += nblk * 256) bcur[i] = 0;
    if (blockIdx.x == 0 && t < 64) {
        int f = dev_sniff(x, t);
        if (t == 0) *flag = f;
    }
    if ((int)blockIdx.x == (nblk > 1 ? 1 : 0)) {
        if (t < 64) {
            int f = dev_sniff(x, t);
            if (t == 0) sflag = f;
        }
        __syncthreads();
        dev_prepB(wl, wh, wm, Bpack, sflag, t);
    }
    grid.sync();

    // ---- phase 1: scat1 (bucketed frontier append; L2-resident hot lines) ----
    {
        int isf32 = *flag;
        for (int i = blockIdx.x * 256 + t; i < E; i += nblk * 256)
            dev_scat1_edge(i, esrc, edst, avl, avh, lab, bcur, etmp, isf32);
    }
    grid.sync();

    // ---- phase 2: gemm (MFMA; streaming writes, isolated from scat1) ----
    {
        int isf32 = *flag;
        int wv = (blockIdx.x * 256 + t) >> 6;
        dev_gemm(x, Bpack, N, xwlh, out /* omlp */, isf32, t, wv, nblk * 4);
    }
    grid.sync();

    // ---- phase 3: scat2 (category-sorted rank) + spmm per bucket ----
    for (int b = blockIdx.x; b < NB2; b += nblk)
        dev_bucket(b, etmp, bcur, N, cb4, epay_lo, xwlh, outlh, t, cnt, startp, cur, tot,
                   stash);
    grid.sync();

    // ---- phase 4: aggregation + attention ----
    {
        int isf32 = *flag;
        int nodeBlocks = (N + 15) / 16;
        for (int vb = blockIdx.x; vb < nodeBlocks; vb += nblk)
            dev_agg_group(vb * 4 + (t >> 6), outlh, epay_lo, cb4, aLF, aHF, aLB, aHB, aLU,
                          aHU, aM, a7, N, out, isf32, t);
    }
}

// ---------------- standalone fallback kernels (R8 path) ----------------

__global__ void k_init(int* __restrict__ bcur, int nbcur, const u16* __restrict__ x,
                       int* __restrict__ flag, const u16* __restrict__ wl,
                       const u16* __restrict__ wh, const u16* __restrict__ wm,
                       u16* __restrict__ Bpack) {
    int t = threadIdx.x;
    int zb = gridDim.x - 1;
    if ((int)blockIdx.x < zb) {
        int i = blockIdx.x * 256 + t;
        if (i < nbcur) bcur[i] = 0;
        if (blockIdx.x == 0 && t < 64) {
            int f = dev_sniff(x, t);
            if (t == 0) *flag = f;
        }
        return;
    }
    __shared__ int sflag;
    if (t < 64) {
        int f = dev_sniff(x, t);
        if (t == 0) sflag = f;
    }
    __syncthreads();
    dev_prepB(wl, wh, wm, Bpack, sflag, t);
}

__global__ void k_scat1(const int* __restrict__ src, const int* __restrict__ dst,
                        const u16* __restrict__ avl, const u16* __restrict__ avh,
                        const int* __restrict__ lab, int E, int* __restrict__ bcur,
                        u64* __restrict__ etmp, const int* __restrict__ flag) {
    int i = blockIdx.x * blockDim.x + threadIdx.x;
    if (i >= E) return;
    dev_scat1_edge(i, src, dst, avl, avh, lab, bcur, etmp, *flag);
}

__launch_bounds__(256) __global__
void k_gemm_mfma(const u16* __restrict__ x, const u16* __restrict__ Bpack, int N,
                 u32* __restrict__ xwlh, float* __restrict__ omlp,
                 const int* __restrict__ flag) {
    int wv = (blockIdx.x * 256 + threadIdx.x) >> 6;
    dev_gemm(x, Bpack, N, xwlh, omlp, *flag, threadIdx.x, wv, gridDim.x * 4);
}

__launch_bounds__(256) __global__
void k_scat2_spmm(const u64* __restrict__ etmp, const int* __restrict__ bcur, int N,
                  int4* __restrict__ cb4, u32* __restrict__ epay_lo,
                  const u32* __restrict__ xwlh, u32* __restrict__ outlh) {
    __shared__ int cnt[192], startp[192], cur[192], tot[64];
    __shared__ u64 stash[BCAP];
    dev_bucket(blockIdx.x, etmp, bcur, N, cb4, epay_lo, xwlh, outlh, threadIdx.x, cnt,
               startp, cur, tot, stash);
}

__launch_bounds__(256) __global__
void k_agg4n(const u32* __restrict__ outlh, const u32* __restrict__ epay_lo,
             const int4* __restrict__ cb4,
             const u16* __restrict__ aLF, const u16* __restrict__ aHF,
             const u16* __restrict__ aLB, const u16* __restrict__ aHB,
             const u16* __restrict__ aLU, const u16* __restrict__ aHU,
             const u16* __restrict__ aM, const u16* __restrict__ a7, int N,
             float* __restrict__ out, const int* __restrict__ flag) {
    int gwave = blockIdx.x * 4 + (threadIdx.x >> 6);
    dev_agg_group(gwave, outlh, epay_lo, cb4, aLF, aHF, aLB, aHB, aLU, aHU, aM, a7, N, out,
                  *flag, threadIdx.x);
}

// ---------------- launcher ----------------

extern "C" void kernel_launch(void* const* d_in, const int* in_sizes, int n_in, void* d_out,
                              int out_size, void* d_ws, size_t ws_size, hipStream_t stream) {
    const u16* x = (const u16*)d_in[0];
    const u16* avl = (const u16*)d_in[1];
    const u16* avh = (const u16*)d_in[2];
    const u16* wl = (const u16*)d_in[3];
    const u16* wh = (const u16*)d_in[4];
    const u16* wm = (const u16*)d_in[5];
    const u16* aLF = (const u16*)d_in[6];
    const u16* aHF = (const u16*)d_in[7];
    const u16* aLB = (const u16*)d_in[8];
    const u16* aHB = (const u16*)d_in[9];
    const u16* aLU = (const u16*)d_in[10];
    const u16* aHU = (const u16*)d_in[11];
    const u16* aM = (const u16*)d_in[12];
    const u16* a7 = (const u16*)d_in[13];
    const int* esrc = (const int*)d_in[14];
    const int* edst = (const int*)d_in[15];
    const int* lab = (const int*)d_in[16];
    float* out = (float*)d_out;

    int N = in_sizes[0] / 64;
    int E = in_sizes[1];
    int NB2 = (N + 63) / 64;  // dst buckets (64 nodes each)

    char* w = (char*)d_ws;
    size_t off = 0;
    auto alloc = [&](size_t bytes) -> char* {
        char* p = w + off;
        off += (bytes + 255) & ~(size_t)255;
        return p;
    };
    int* flag = (int*)alloc(256);
    int* bcur = (int*)alloc((size_t)NB2 * 16 * 4);  // cursors padded to own 64B line
    u16* Bpack = (u16*)alloc(12 * 2 * 64 * 8 * 2);  // 24 KB fragment-ordered weights
    int4* cb4 = (int4*)alloc((size_t)N * 16);       // per-node category boundaries
    u64* etmp = (u64*)alloc((size_t)NB2 * BCAP * 8);
    u32* epay_lo = (u32*)alloc((size_t)NB2 * BCAP * 4);
    u32* xwlh = (u32*)alloc((size_t)N * 64 * 4);
    u32* outlh = (u32*)alloc((size_t)N * 64 * 4);

    if (ws_size < off) {
        k_sentinel<<<(out_size + 255) / 256, 256, 0, stream>>>(out, out_size, 1000.0f);
        return;
    }

    // ---- try the 1-launch cooperative path ----
    bool launched = false;
    int coopOK = 0, numCU = 0, maxb = 0;
    (void)hipDeviceGetAttribute(&coopOK, hipDeviceAttributeCooperativeLaunch, 0);
    (void)hipDeviceGetAttribute(&numCU, hipDeviceAttributeMultiprocessorCount, 0);
    hipError_t occErr =
        hipOccupancyMaxActiveBlocksPerMultiprocessor(&maxb, (const void*)k_mega, 256, 0);
    if (coopOK && occErr == hipSuccess && numCU > 0 && maxb > 0) {
        int grid = numCU * maxb;
        if (grid > 2048) grid = 2048;
        if (grid >= 64) {
            void* args[] = {&x,   &avl,  &avh,  &wl,    &wh,   &wm,      &aLF,  &aHF,
                            &aLB, &aHB,  &aLU,  &aHU,   &aM,   &a7,      &esrc, &edst,
                            &lab, &N,    &E,    &NB2,   &flag, &bcur,    &Bpack, &cb4,
                            &etmp, &epay_lo, &xwlh, &outlh, &out};
            hipError_t err = hipLaunchCooperativeKernel((const void*)k_mega, dim3(grid),
                                                        dim3(256), args, 0, stream);
            launched = (err == hipSuccess);
        }
    }
    if (launched) return;

    // ---- fallback: R8 5-kernel path ----
    int nbcur = NB2 * 16;
    int ZB = (nbcur + 255) / 256;
    k_init<<<ZB + 1, 256, 0, stream>>>(bcur, nbcur, x, flag, wl, wh, wm, Bpack);
    k_scat1<<<(E + 255) / 256, 256, 0, stream>>>(esrc, edst, avl, avh, lab, E, bcur, etmp,
                                                 flag);
    int ntiles = (N + 15) / 16;
    int gemmBlocks = (ntiles + 3) / 4;
    k_gemm_mfma<<<gemmBlocks, 256, 0, stream>>>(x, Bpack, N, xwlh, out /* omlp */, flag);
    k_scat2_spmm<<<NB2, 256, 0, stream>>>(etmp, bcur, N, cb4, epay_lo, xwlh, outlh);
    int nodeBlocks = (N + 15) / 16;
    k_agg4n<<<nodeBlocks, 256, 0, stream>>>(outlh, epay_lo, cb4, aLF, aHF, aLB, aHB, aLU, aHU,
                                            aM, a7, N, out, flag);
}

// Round 10
// 390.111 us; speedup vs baseline: 1.9172x; 1.9172x over previous
//
#include <hip/hip_runtime.h>
#include <hip/hip_bf16.h>

typedef unsigned int u32;
typedef unsigned short u16;
typedef unsigned long long u64;

typedef __attribute__((ext_vector_type(8))) short bf16x8;
typedef __attribute__((ext_vector_type(4))) float f32x4;
typedef __attribute__((ext_vector_type(2))) float f32x2;

#define BCAP 1536  // edge capacity per 64-node bucket (mean 1024, sigma 32 -> 16-sigma headroom)

// bf16 = top 16 bits of fp32; RNE pack
static __device__ __forceinline__ float bflo(u32 u) { return __uint_as_float(u << 16); }
static __device__ __forceinline__ float bfhi(u32 u) { return __uint_as_float(u & 0xFFFF0000u); }
static __device__ __forceinline__ float bf2f(u16 u) { return __uint_as_float((u32)u << 16); }
static __device__ __forceinline__ u32 f2bf(float f) {
    u32 u = __float_as_uint(f);
    return (u + 0x7FFFu + ((u >> 16) & 1u)) >> 16;
}
static __device__ __forceinline__ u32 packbf(float lo, float hi) {
    return f2bf(lo) | (f2bf(hi) << 16);
}
static __device__ __forceinline__ float ldf(const u16* p16, int idx, int isf32) {
    return isf32 ? ((const float*)p16)[idx] : bf2f(p16[idx]);
}
// load 4 consecutive attention-vector elements [4*q .. 4*q+3]
static __device__ __forceinline__ void load4(const u16* p, int q, int isf32, float* v) {
    if (isf32) {
        float4 t = ((const float4*)p)[q];
        v[0] = t.x; v[1] = t.y; v[2] = t.z; v[3] = t.w;
    } else {
        u32 a = ((const u32*)p)[q * 2], b = ((const u32*)p)[q * 2 + 1];
        v[0] = bflo(a); v[1] = bfhi(a); v[2] = bflo(b); v[3] = bfhi(b);
    }
}
static __device__ __forceinline__ float sanitize(float v, float code) {
    return (fabsf(v) < 1e30f) ? v : code;
}

// unpack u32 (bf16 L | bf16 H<<16) into {L, H} fp32 pair
static __device__ __forceinline__ f32x2 up2(u32 u) {
    f32x2 r;
    r.x = __uint_as_float(u << 16);
    r.y = __uint_as_float(u & 0xFFFF0000u);
    return r;
}
// packed-pair fp32 FMA / ADD (VOP3P) — one instruction for both (L,H) planes
static __device__ __forceinline__ void pk_fma(f32x2& d, f32x2 a, f32x2 b) {
    asm("v_pk_fma_f32 %0, %1, %2, %0" : "+v"(d) : "v"(a), "v"(b));
}
static __device__ __forceinline__ void pk_add(f32x2& d, f32x2 a) {
    asm("v_pk_add_f32 %0, %1, %0" : "+v"(d) : "v"(a));
}

static __device__ __forceinline__ float wave_sum(float v) {
#pragma unroll
    for (int o = 32; o; o >>= 1) v += __shfl_xor(v, o, 64);
    return v;
}
// sum within 16-lane group (lanes grouped by lane>>4)
static __device__ __forceinline__ float group_sum(float v) {
#pragma unroll
    for (int o = 8; o; o >>= 1) v += __shfl_xor(v, o, 64);
    return v;
}

// ---------------- diagnostics / utility ----------------

__global__ void k_sentinel(float* __restrict__ out, int n, float val) {
    int i = blockIdx.x * blockDim.x + threadIdx.x;
    if (i < n) out[i] = val;
}

// dtype sniff over first 64x64 values of x (run by one 64-lane wave; result for lane 0)
static __device__ __forceinline__ int dev_sniff(const u16* x, int lane) {
    int wild = 0;
    for (int k = 0; k < 64; k++) {
        u32 u = x[lane * 64 + k];
        int e = (u >> 7) & 0xFF;
        if (e < 96 || e > 135) wild++;
    }
    float tot = wave_sum((float)wild);
    return (tot > 200.f) ? 1 : 0;
}

// pack W_low/W_high/W_mlp into MFMA fragment order (256 threads cooperate)
static __device__ void dev_prepB(const u16* wl, const u16* wh, const u16* wm, u16* Bpack,
                                 int isf32, int t) {
    for (int idx = t; idx < 12 * 2 * 64; idx += 256) {
        int slot = idx >> 6;
        int ln = idx & 63;
        int ct = slot >> 1, c = slot & 1;
        int mat = ct >> 2;
        const u16* W = (mat == 0) ? wl : (mat == 1) ? wh : wm;
        int col = (ct & 3) * 16 + (ln & 15);
        int kbase = c * 32 + (ln >> 4) * 8;
        u16* dst = Bpack + (size_t)idx * 8;
#pragma unroll
        for (int j = 0; j < 8; j++)
            dst[j] = (u16)f2bf(ldf(W, (kbase + j) * 64 + col, isf32));
    }
}

// ---------------- init: zero bucket cursors + dtype sniff + weight packing ----------------
// NOTE (R9 lesson): do NOT fuse the pipeline into one cooperative kernel — the fused
// kernel pays the max resource footprint of all phases (104 VGPR + 15KB LDS), capping
// the latency-bound gather phases at 4 blocks/CU and costing ~2x (609 vs ~290 us).
__global__ void k_init(int* __restrict__ bcur, int nbcur, const u16* __restrict__ x,
                       int* __restrict__ flag, const u16* __restrict__ wl,
                       const u16* __restrict__ wh, const u16* __restrict__ wm,
                       u16* __restrict__ Bpack) {
    int t = threadIdx.x;
    int zb = gridDim.x - 1;
    if ((int)blockIdx.x < zb) {
        int i = blockIdx.x * 256 + t;
        if (i < nbcur) bcur[i] = 0;
        if (blockIdx.x == 0 && t < 64) {
            int f = dev_sniff(x, t);
            if (t == 0) *flag = f;
        }
        return;
    }
    // prepB block (computes its own sniff locally to avoid cross-block race on flag)
    __shared__ int sflag;
    if (t < 64) {
        int f = dev_sniff(x, t);
        if (t == 0) sflag = f;
    }
    __syncthreads();
    dev_prepB(wl, wh, wm, Bpack, sflag, t);
}

// ---------------- scat1: bucketed append into fixed-capacity bucket blocks ----------------
// Bucket = 64 consecutive dst nodes, block capacity BCAP. Append at bucket frontier
// (hot set ~1563 lines, L2-resident -> full-line writeback). dloc (6 bits) in payload
// bits 22..27, fake in 20..21, src in 0..19. Kept UNFUSED from gemm (R5 lesson:
// streaming writers evict the frontier lines -> 8x write amplification).
__global__ void k_scat1(const int* __restrict__ src, const int* __restrict__ dst,
                        const u16* __restrict__ avl, const u16* __restrict__ avh,
                        const int* __restrict__ lab, int E, int* __restrict__ bcur,
                        u64* __restrict__ etmp, const int* __restrict__ flag) {
    int i = blockIdx.x * blockDim.x + threadIdx.x;
    if (i >= E) return;
    int isf32 = *flag;
    int d = dst[i];
    int b = d >> 6;
    int base = b << 6;
    int rank = atomicAdd(&bcur[b * 16], 1);  // counters padded to own 64B line
    if (rank >= BCAP) return;                // statistically impossible (16 sigma)
    int s = src[i];
    int sl = lab[s], dl = lab[d];
    int fake = (sl < 0 || dl < 0) ? 2 : ((sl != dl) ? 1 : 0);
    u32 lo32 = (u32)s | ((u32)fake << 20) | ((u32)(d - base) << 22);
    u32 hi32 = isf32 ? packbf(((const float*)avl)[i], ((const float*)avh)[i])
                     : ((u32)avl[i] | ((u32)avh[i] << 16));
    etmp[(size_t)b * BCAP + rank] = ((u64)hi32 << 32) | lo32;
}

// ---------------- phase A: x @ {W_low, W_high, W_mlp} via MFMA ----------------
__launch_bounds__(256) __global__
void k_gemm_mfma(const u16* __restrict__ x, const u16* __restrict__ Bpack, int N,
                 u32* __restrict__ xwlh, float* __restrict__ omlp,
                 const int* __restrict__ flag) {
    int isf32 = *flag;
    int lane = threadIdx.x & 63;
    int wv = (blockIdx.x * 256 + threadIdx.x) >> 6;
    int nw = gridDim.x * 4;
    int m = lane & 15, quad = lane >> 4;
    int ntiles = (N + 15) >> 4;
    for (int tile = wv; tile < ntiles; tile += nw) {
        int r0 = tile * 16;
        int arow = min(r0 + m, N - 1);
        bf16x8 a[2];
#pragma unroll
        for (int c = 0; c < 2; c++) {
            int base = arow * 64 + c * 32 + quad * 8;
            if (isf32) {
                const float4* xf = (const float4*)x;
                int q = (base >> 2);
                float4 t0 = xf[q], t1 = xf[q + 1];
                a[c][0] = (short)f2bf(t0.x); a[c][1] = (short)f2bf(t0.y);
                a[c][2] = (short)f2bf(t0.z); a[c][3] = (short)f2bf(t0.w);
                a[c][4] = (short)f2bf(t1.x); a[c][5] = (short)f2bf(t1.y);
                a[c][6] = (short)f2bf(t1.z); a[c][7] = (short)f2bf(t1.w);
            } else {
                a[c] = *(const bf16x8*)(x + base);
            }
        }
        f32x4 acc[12];
#pragma unroll
        for (int t = 0; t < 12; t++) acc[t] = (f32x4){0.f, 0.f, 0.f, 0.f};
#pragma unroll
        for (int t = 0; t < 12; t++) {
#pragma unroll
            for (int c = 0; c < 2; c++) {
                bf16x8 b = *(const bf16x8*)(Bpack + (size_t)((t * 2 + c) * 64 + lane) * 8);
                acc[t] = __builtin_amdgcn_mfma_f32_16x16x32_bf16(a[c], b, acc[t], 0, 0, 0);
            }
        }
        // C/D: col = lane&15, row = quad*4 + reg
#pragma unroll
        for (int t = 0; t < 4; t++) {
#pragma unroll
            for (int r = 0; r < 4; r++) {
                int row = r0 + quad * 4 + r;
                if (row < N) {
                    int o = row * 64 + t * 16 + m;
                    xwlh[o] = packbf(acc[t][r], acc[t + 4][r]);
                    omlp[o] = fmaxf(acc[t + 8][r], 0.f);
                }
            }
        }
    }
}

// ---------------- fused: scat2 (category-sorted rank within bucket) + spmm ----------------
// Phase A: load this bucket's edges into registers, count per (dloc, fake) in LDS.
// Prefix: per-node category boundaries; store int4 (s, c1, c2, e) per node for agg.
// Phase B: place edges (category-sorted within node) into LDS stash + epay_lo.
// Phase C: spmm for the bucket's own 64 nodes — payloads from LDS stash only,
// features gathered from xwlh (full 256B row per edge), unroll-4 (4 gathers in flight).
__launch_bounds__(256) __global__
void k_scat2_spmm(const u64* __restrict__ etmp, const int* __restrict__ bcur, int N,
                  int4* __restrict__ cb4, u32* __restrict__ epay_lo,
                  const u32* __restrict__ xwlh, u32* __restrict__ outlh) {
    __shared__ int cnt[192], startp[192], cur[192], tot[64];
    __shared__ u64 stash[BCAP];
    int b = blockIdx.x;
    int base = b << 6;
    int ebase = b * BCAP;
    int t = threadIdx.x;
    if (t < 192) cnt[t] = 0;
    __syncthreads();
    int cntE = min(bcur[b * 16], BCAP);
    // ---- phase A: load to regs + count ----
    u64 ph[6];  // BCAP/256 = 6 max edges per thread
#pragma unroll
    for (int j = 0; j < 6; j++) {
        int e = t + j * 256;
        if (e < cntE) {
            u64 p = etmp[(size_t)ebase + e];
            ph[j] = p;
            int dl3 = ((int)(p >> 22) & 63) * 3 + ((int)(p >> 20) & 3);
            atomicAdd(&cnt[dl3], 1);
        }
    }
    __syncthreads();
    // ---- prefix over nodes (and categories within node) ----
    if (t < 64) tot[t] = cnt[t * 3] + cnt[t * 3 + 1] + cnt[t * 3 + 2];
    __syncthreads();
    for (int d = 1; d < 64; d <<= 1) {
        int v = 0;
        if (t < 64 && t >= d) v = tot[t - d];
        __syncthreads();
        if (t < 64) tot[t] += v;
        __syncthreads();
    }
    if (t < 64) {
        int c0 = cnt[t * 3], c1 = cnt[t * 3 + 1], c2 = cnt[t * 3 + 2];
        int own = c0 + c1 + c2;
        int ex = tot[t] - own;
        int s0 = ex, s1 = ex + c0, s2 = ex + c0 + c1;
        startp[t * 3] = s0;
        startp[t * 3 + 1] = s1;
        startp[t * 3 + 2] = s2;
        cur[t * 3] = s0;
        cur[t * 3 + 1] = s1;
        cur[t * 3 + 2] = s2;
        int node = base + t;
        if (node < N) {
            int4 cb;
            cb.x = ebase + s0;
            cb.y = ebase + s1;
            cb.z = ebase + s2;
            cb.w = ebase + ex + own;
            cb4[node] = cb;
        }
    }
    __syncthreads();
    // ---- phase B: place (category-sorted within each node) ----
#pragma unroll
    for (int j = 0; j < 6; j++) {
        int e = t + j * 256;
        if (e < cntE) {
            u64 p = ph[j];
            int dl3 = ((int)(p >> 22) & 63) * 3 + ((int)(p >> 20) & 3);
            int rank = atomicAdd(&cur[dl3], 1);
            stash[rank] = p;
            epay_lo[(size_t)ebase + rank] = (u32)p;
        }
    }
    __syncthreads();
    // ---- phase C: spmm for nodes [base, base+64), unroll-4 (4 gathers in flight) ----
    int g = t & 15, grp = t >> 4;  // 16 feature-lanes x 16 groups
    const uint4* tab = (const uint4*)xwlh + g;
#pragma unroll
    for (int it = 0; it < 4; it++) {
        int dloc = it * 16 + grp;
        int node = base + dloc;
        if (node >= N) continue;
        int sR = startp[dloc * 3];
        int eR = startp[dloc * 3 + 2] + cnt[dloc * 3 + 2];
        f32x2 acc[4];
#pragma unroll
        for (int k = 0; k < 4; k++) acc[k] = (f32x2){0.f, 0.f};
        int idx = sR;
        for (; idx + 3 < eR; idx += 4) {
            u64 p0 = stash[idx], p1 = stash[idx + 1], p2 = stash[idx + 2], p3 = stash[idx + 3];
            uint4 R0 = tab[(size_t)(p0 & 0xFFFFF) << 4];
            uint4 R1 = tab[(size_t)(p1 & 0xFFFFF) << 4];
            uint4 R2 = tab[(size_t)(p2 & 0xFFFFF) << 4];
            uint4 R3 = tab[(size_t)(p3 & 0xFFFFF) << 4];
            f32x2 w0 = up2((u32)(p0 >> 32)), w1 = up2((u32)(p1 >> 32));
            f32x2 w2 = up2((u32)(p2 >> 32)), w3 = up2((u32)(p3 >> 32));
            pk_fma(acc[0], up2(R0.x), w0);
            pk_fma(acc[1], up2(R0.y), w0);
            pk_fma(acc[2], up2(R0.z), w0);
            pk_fma(acc[3], up2(R0.w), w0);
            pk_fma(acc[0], up2(R1.x), w1);
            pk_fma(acc[1], up2(R1.y), w1);
            pk_fma(acc[2], up2(R1.z), w1);
            pk_fma(acc[3], up2(R1.w), w1);
            pk_fma(acc[0], up2(R2.x), w2);
            pk_fma(acc[1], up2(R2.y), w2);
            pk_fma(acc[2], up2(R2.z), w2);
            pk_fma(acc[3], up2(R2.w), w2);
            pk_fma(acc[0], up2(R3.x), w3);
            pk_fma(acc[1], up2(R3.y), w3);
            pk_fma(acc[2], up2(R3.z), w3);
            pk_fma(acc[3], up2(R3.w), w3);
        }
        for (; idx < eR; idx++) {
            u64 p0 = stash[idx];
            uint4 R0 = tab[(size_t)(p0 & 0xFFFFF) << 4];
            f32x2 w0 = up2((u32)(p0 >> 32));
            pk_fma(acc[0], up2(R0.x), w0);
            pk_fma(acc[1], up2(R0.y), w0);
            pk_fma(acc[2], up2(R0.z), w0);
            pk_fma(acc[3], up2(R0.w), w0);
        }
        uint4 W;
        W.x = packbf(fmaxf(acc[0].x, 0.f), fmaxf(acc[0].y, 0.f));
        W.y = packbf(fmaxf(acc[1].x, 0.f), fmaxf(acc[1].y, 0.f));
        W.z = packbf(fmaxf(acc[2].x, 0.f), fmaxf(acc[2].y, 0.f));
        W.w = packbf(fmaxf(acc[3].x, 0.f), fmaxf(acc[3].y, 0.f));
        ((uint4*)(outlh + (size_t)node * 64))[g] = W;
    }
}

// ---------------- phase C+D fused: prefix-snapshot aggregation + attention ----------------
// 4 nodes per wave (16-lane group per node, feature dwords 4g..4g+3). Segments are
// category-sorted [homo|hete|unk]; ONE long unroll-4 sweep accumulates a running sum
// (4 pk_add/edge, 4 gathers in flight); the accumulator is SNAPSHOTTED when the index
// crosses c1 (->S1=Ho) and c2 (->S2=Ho+He). He=S2-S1, Un=T-S2. (R7/R8 lesson: keep
// ONE long sweep for MLP; category masks and split sweeps both cost more than they save.)

__launch_bounds__(256) __global__
void k_agg4n(const u32* __restrict__ outlh, const u32* __restrict__ epay_lo,
             const int4* __restrict__ cb4,
             const u16* __restrict__ aLF, const u16* __restrict__ aHF,
             const u16* __restrict__ aLB, const u16* __restrict__ aHB,
             const u16* __restrict__ aLU, const u16* __restrict__ aHU,
             const u16* __restrict__ aM, const u16* __restrict__ a7, int N,
             float* __restrict__ out, const int* __restrict__ flag) {
    int isf32 = *flag;
    int lane = threadIdx.x & 63;
    int gwave = blockIdx.x * 4 + (threadIdx.x >> 6);
    int g = lane & 15, gi = lane >> 4;
    int node = gwave * 4 + gi;
    bool vn = node < N;
    int4 cb = vn ? cb4[node] : (int4){0, 0, 0, 0};
    int s = cb.x, c1 = cb.y, c2 = cb.z, e = cb.w;
    const uint4* tab = (const uint4*)outlh + g;
    f32x2 acc[4], S1[4], S2[4];
#pragma unroll
    for (int k = 0; k < 4; k++) {
        acc[k] = (f32x2){0.f, 0.f};
        S1[k] = (f32x2){0.f, 0.f};
        S2[k] = (f32x2){0.f, 0.f};
    }
#define AGG_EDGE(R)                    \
    pk_add(acc[0], up2(R.x));          \
    pk_add(acc[1], up2(R.y));          \
    pk_add(acc[2], up2(R.z));          \
    pk_add(acc[3], up2(R.w));
#define AGG_CHK(q)                                                        \
    if ((q) == c1) { S1[0] = acc[0]; S1[1] = acc[1]; S1[2] = acc[2]; S1[3] = acc[3]; } \
    if ((q) == c2) { S2[0] = acc[0]; S2[1] = acc[1]; S2[2] = acc[2]; S2[3] = acc[3]; }
    int tt = s;
    for (; tt + 3 < e; tt += 4) {
        u32 p0 = epay_lo[tt], p1 = epay_lo[tt + 1];
        u32 p2 = epay_lo[tt + 2], p3 = epay_lo[tt + 3];
        uint4 R0 = tab[(size_t)(p0 & 0xFFFFF) << 4];
        uint4 R1 = tab[(size_t)(p1 & 0xFFFFF) << 4];
        uint4 R2 = tab[(size_t)(p2 & 0xFFFFF) << 4];
        uint4 R3 = tab[(size_t)(p3 & 0xFFFFF) << 4];
        AGG_EDGE(R0); AGG_CHK(tt + 1);
        AGG_EDGE(R1); AGG_CHK(tt + 2);
        AGG_EDGE(R2); AGG_CHK(tt + 3);
        AGG_EDGE(R3); AGG_CHK(tt + 4);
    }
    for (; tt < e; tt++) {
        u32 p0 = epay_lo[tt];
        uint4 R0 = tab[(size_t)(p0 & 0xFFFFF) << 4];
        AGG_EDGE(R0); AGG_CHK(tt + 1);
    }
#undef AGG_EDGE
#undef AGG_CHK
    float heL[4], heH[4], hoL[4], hoH[4], unL[4], unH[4];
#pragma unroll
    for (int k = 0; k < 4; k++) {
        hoL[k] = S1[k].x;            hoH[k] = S1[k].y;
        heL[k] = S2[k].x - S1[k].x;  heH[k] = S2[k].y - S1[k].y;
        unL[k] = acc[k].x - S2[k].x; unH[k] = acc[k].y - S2[k].y;
    }
    // attention-vector slices for this lane's 4 features (same across groups)
    float vLF[4], vHF[4], vLB[4], vHB[4], vLU[4], vHU[4], vM[4];
    load4(aLF, g, isf32, vLF);
    load4(aHF, g, isf32, vHF);
    load4(aLB, g, isf32, vLB);
    load4(aHB, g, isf32, vHB);
    load4(aLU, g, isf32, vLU);
    load4(aHU, g, isf32, vHU);
    load4(aM, g, isf32, vM);
    float mvv[4] = {0.f, 0.f, 0.f, 0.f};
    if (vn) {
        float4 MV = ((const float4*)(out + (size_t)node * 64))[g];  // omlp staged in d_out
        mvv[0] = MV.x; mvv[1] = MV.y; mvv[2] = MV.z; mvv[3] = MV.w;
    }

    // 7 dot products; each group reduces over its own 16 lanes (full feature dim)
    float p0 = 0, p1 = 0, p2 = 0, p3 = 0, p4 = 0, p5 = 0, p6 = 0;
#pragma unroll
    for (int k = 0; k < 4; k++) {
        p0 += heL[k] * vLF[k];
        p1 += heH[k] * vHF[k];
        p2 += hoL[k] * vLB[k];
        p3 += hoH[k] * vHB[k];
        p4 += unL[k] * vLU[k];
        p5 += unH[k] * vHU[k];
        p6 += mvv[k] * vM[k];
    }
    float d0 = group_sum(p0), d1 = group_sum(p1), d2 = group_sum(p2), d3 = group_sum(p3);
    float d4 = group_sum(p4), d5 = group_sum(p5), d6 = group_sum(p6);

    float f[7];
    f[0] = 1.f / (1.f + expf(-d0));
    f[1] = 1.f / (1.f + expf(-d1));
    f[2] = 1.f / (1.f + expf(-d2));
    f[3] = 1.f / (1.f + expf(-d3));
    f[4] = 1.f / (1.f + expf(-d4));
    f[5] = 1.f / (1.f + expf(-d5));
    f[6] = 1.f / (1.f + expf(-d6));

    float z[7];
#pragma unroll
    for (int jj = 0; jj < 7; jj++) {
        float acc7 = 0.f;
#pragma unroll
        for (int i = 0; i < 7; i++) acc7 += f[i] * ldf(a7, i * 7 + jj, isf32);
        z[jj] = acc7 * (1.f / 7.f);
    }
    float m = z[0];
#pragma unroll
    for (int jj = 1; jj < 7; jj++) m = fmaxf(m, z[jj]);
    float wsum = 0.f;
    float wv[7];
#pragma unroll
    for (int jj = 0; jj < 7; jj++) { wv[jj] = expf(z[jj] - m); wsum += wv[jj]; }
    float s7 = 7.f / wsum;

    if (vn) {
        float4 W;
        float o0 = wv[0] * heL[0] + wv[1] * heH[0] + wv[2] * hoL[0] + wv[3] * hoH[0] +
                   wv[4] * unL[0] + wv[5] * unH[0] + wv[6] * mvv[0];
        float o1 = wv[0] * heL[1] + wv[1] * heH[1] + wv[2] * hoL[1] + wv[3] * hoH[1] +
                   wv[4] * unL[1] + wv[5] * unH[1] + wv[6] * mvv[1];
        float o2 = wv[0] * heL[2] + wv[1] * heH[2] + wv[2] * hoL[2] + wv[3] * hoH[2] +
                   wv[4] * unL[2] + wv[5] * unH[2] + wv[6] * mvv[2];
        float o3 = wv[0] * heL[3] + wv[1] * heH[3] + wv[2] * hoL[3] + wv[3] * hoH[3] +
                   wv[4] * unL[3] + wv[5] * unH[3] + wv[6] * mvv[3];
        W.x = sanitize(o0 * s7, 333.f);
        W.y = sanitize(o1 * s7, 333.f);
        W.z = sanitize(o2 * s7, 333.f);
        W.w = sanitize(o3 * s7, 333.f);
        ((float4*)(out + (size_t)node * 64))[g] = W;
    }
}

// ---------------- launcher ----------------

extern "C" void kernel_launch(void* const* d_in, const int* in_sizes, int n_in, void* d_out,
                              int out_size, void* d_ws, size_t ws_size, hipStream_t stream) {
    const u16* x = (const u16*)d_in[0];
    const u16* avl = (const u16*)d_in[1];
    const u16* avh = (const u16*)d_in[2];
    const u16* wl = (const u16*)d_in[3];
    const u16* wh = (const u16*)d_in[4];
    const u16* wm = (const u16*)d_in[5];
    const u16* aLF = (const u16*)d_in[6];
    const u16* aHF = (const u16*)d_in[7];
    const u16* aLB = (const u16*)d_in[8];
    const u16* aHB = (const u16*)d_in[9];
    const u16* aLU = (const u16*)d_in[10];
    const u16* aHU = (const u16*)d_in[11];
    const u16* aM = (const u16*)d_in[12];
    const u16* a7 = (const u16*)d_in[13];
    const int* esrc = (const int*)d_in[14];
    const int* edst = (const int*)d_in[15];
    const int* lab = (const int*)d_in[16];
    float* out = (float*)d_out;

    const int N = in_sizes[0] / 64;
    const int E = in_sizes[1];

    int NB2 = (N + 63) / 64;  // dst buckets (64 nodes each)

    char* w = (char*)d_ws;
    size_t off = 0;
    auto alloc = [&](size_t bytes) -> char* {
        char* p = w + off;
        off += (bytes + 255) & ~(size_t)255;
        return p;
    };
    int* flag = (int*)alloc(256);
    int* bcur = (int*)alloc((size_t)NB2 * 16 * 4);  // cursors padded to own 64B line
    u16* Bpack = (u16*)alloc(12 * 2 * 64 * 8 * 2);  // 24 KB fragment-ordered weights
    int4* cb4 = (int4*)alloc((size_t)N * 16);       // per-node category boundaries
    u64* etmp = (u64*)alloc((size_t)NB2 * BCAP * 8);
    u32* epay_lo = (u32*)alloc((size_t)NB2 * BCAP * 4);
    u32* xwlh = (u32*)alloc((size_t)N * 64 * 4);
    u32* outlh = (u32*)alloc((size_t)N * 64 * 4);

    if (ws_size < off) {
        k_sentinel<<<(out_size + 255) / 256, 256, 0, stream>>>(out, out_size, 1000.0f);
        return;
    }

    int nbcur = NB2 * 16;
    int ZB = (nbcur + 255) / 256;
    k_init<<<ZB + 1, 256, 0, stream>>>(bcur, nbcur, x, flag, wl, wh, wm, Bpack);

    k_scat1<<<(E + 255) / 256, 256, 0, stream>>>(esrc, edst, avl, avh, lab, E, bcur, etmp,
                                                 flag);

    int ntiles = (N + 15) / 16;  // one 16-row tile per wave
    int gemmBlocks = (ntiles + 3) / 4;
    k_gemm_mfma<<<gemmBlocks, 256, 0, stream>>>(x, Bpack, N, xwlh,
                                                out /* omlp staged in d_out */, flag);

    k_scat2_spmm<<<NB2, 256, 0, stream>>>(etmp, bcur, N, cb4, epay_lo, xwlh, outlh);

    int nodeBlocks = (N + 15) / 16;  // 16 nodes per block (4 waves x 4 nodes)
    k_agg4n<<<nodeBlocks, 256, 0, stream>>>(outlh, epay_lo, cb4, aLF, aHF, aLB, aHB, aLU, aHU,
                                            aM, a7, N, out, flag);
}

// Round 11
// 389.137 us; speedup vs baseline: 1.9220x; 1.0025x over previous
//
#include <hip/hip_runtime.h>
#include <hip/hip_bf16.h>

typedef unsigned int u32;
typedef unsigned short u16;
typedef unsigned long long u64;

typedef __attribute__((ext_vector_type(8))) short bf16x8;
typedef __attribute__((ext_vector_type(4))) float f32x4;
typedef __attribute__((ext_vector_type(2))) float f32x2;

#define BCAP 1536   // per-bucket epay region (mean 1024, 16-sigma headroom)
#define SCAP 256    // per-XCD sub-bucket staging capacity (mean 128, ~11 sigma)
#define NXCD 8
#define STASH_CAP 2048  // 8 * SCAP upper bound for LDS stash

// bf16 = top 16 bits of fp32; RNE pack
static __device__ __forceinline__ float bflo(u32 u) { return __uint_as_float(u << 16); }
static __device__ __forceinline__ float bfhi(u32 u) { return __uint_as_float(u & 0xFFFF0000u); }
static __device__ __forceinline__ float bf2f(u16 u) { return __uint_as_float((u32)u << 16); }
static __device__ __forceinline__ u32 f2bf(float f) {
    u32 u = __float_as_uint(f);
    return (u + 0x7FFFu + ((u >> 16) & 1u)) >> 16;
}
static __device__ __forceinline__ u32 packbf(float lo, float hi) {
    return f2bf(lo) | (f2bf(hi) << 16);
}
static __device__ __forceinline__ float ldf(const u16* p16, int idx, int isf32) {
    return isf32 ? ((const float*)p16)[idx] : bf2f(p16[idx]);
}
// load 4 consecutive attention-vector elements [4*q .. 4*q+3]
static __device__ __forceinline__ void load4(const u16* p, int q, int isf32, float* v) {
    if (isf32) {
        float4 t = ((const float4*)p)[q];
        v[0] = t.x; v[1] = t.y; v[2] = t.z; v[3] = t.w;
    } else {
        u32 a = ((const u32*)p)[q * 2], b = ((const u32*)p)[q * 2 + 1];
        v[0] = bflo(a); v[1] = bfhi(a); v[2] = bflo(b); v[3] = bfhi(b);
    }
}
static __device__ __forceinline__ float sanitize(float v, float code) {
    return (fabsf(v) < 1e30f) ? v : code;
}

// unpack u32 (bf16 L | bf16 H<<16) into {L, H} fp32 pair
static __device__ __forceinline__ f32x2 up2(u32 u) {
    f32x2 r;
    r.x = __uint_as_float(u << 16);
    r.y = __uint_as_float(u & 0xFFFF0000u);
    return r;
}
// packed-pair fp32 FMA / ADD (VOP3P) — one instruction for both (L,H) planes
static __device__ __forceinline__ void pk_fma(f32x2& d, f32x2 a, f32x2 b) {
    asm("v_pk_fma_f32 %0, %1, %2, %0" : "+v"(d) : "v"(a), "v"(b));
}
static __device__ __forceinline__ void pk_add(f32x2& d, f32x2 a) {
    asm("v_pk_add_f32 %0, %1, %0" : "+v"(d) : "v"(a));
}

static __device__ __forceinline__ float wave_sum(float v) {
#pragma unroll
    for (int o = 32; o; o >>= 1) v += __shfl_xor(v, o, 64);
    return v;
}
// sum within 16-lane group (lanes grouped by lane>>4)
static __device__ __forceinline__ float group_sum(float v) {
#pragma unroll
    for (int o = 8; o; o >>= 1) v += __shfl_xor(v, o, 64);
    return v;
}

// ---------------- diagnostics / utility ----------------

__global__ void k_sentinel(float* __restrict__ out, int n, float val) {
    int i = blockIdx.x * blockDim.x + threadIdx.x;
    if (i < n) out[i] = val;
}

// dtype sniff over first 64x64 values of x (run by one 64-lane wave; result for lane 0)
static __device__ __forceinline__ int dev_sniff(const u16* x, int lane) {
    int wild = 0;
    for (int k = 0; k < 64; k++) {
        u32 u = x[lane * 64 + k];
        int e = (u >> 7) & 0xFF;
        if (e < 96 || e > 135) wild++;
    }
    float tot = wave_sum((float)wild);
    return (tot > 200.f) ? 1 : 0;
}

// pack W_low/W_high/W_mlp into MFMA fragment order (256 threads cooperate)
static __device__ void dev_prepB(const u16* wl, const u16* wh, const u16* wm, u16* Bpack,
                                 int isf32, int t) {
    for (int idx = t; idx < 12 * 2 * 64; idx += 256) {
        int slot = idx >> 6;
        int ln = idx & 63;
        int ct = slot >> 1, c = slot & 1;
        int mat = ct >> 2;
        const u16* W = (mat == 0) ? wl : (mat == 1) ? wh : wm;
        int col = (ct & 3) * 16 + (ln & 15);
        int kbase = c * 32 + (ln >> 4) * 8;
        u16* dst = Bpack + (size_t)idx * 8;
#pragma unroll
        for (int j = 0; j < 8; j++)
            dst[j] = (u16)f2bf(ldf(W, (kbase + j) * 64 + col, isf32));
    }
}

// ---------------- init: zero bucket cursors + dtype sniff + weight packing ----------------
// NOTE (R9 lesson): do NOT fuse the pipeline into one cooperative kernel — the fused
// kernel pays the max resource footprint of all phases, capping the latency-bound
// gather phases at 4 blocks/CU (609 vs ~290 us).
__global__ void k_init(int* __restrict__ bcur, int nbcur, const u16* __restrict__ x,
                       int* __restrict__ flag, const u16* __restrict__ wl,
                       const u16* __restrict__ wh, const u16* __restrict__ wm,
                       u16* __restrict__ Bpack) {
    int t = threadIdx.x;
    int zb = gridDim.x - 1;
    if ((int)blockIdx.x < zb) {
        int i = blockIdx.x * 256 + t;
        if (i < nbcur) bcur[i] = 0;
        if (blockIdx.x == 0 && t < 64) {
            int f = dev_sniff(x, t);
            if (t == 0) *flag = f;
        }
        return;
    }
    // prepB block (computes its own sniff locally to avoid cross-block race on flag)
    __shared__ int sflag;
    if (t < 64) {
        int f = dev_sniff(x, t);
        if (t == 0) sflag = f;
    }
    __syncthreads();
    dev_prepB(wl, wh, wm, Bpack, sflag, t);
}

// ---------------- scat1: XCD-private bucketed append ----------------
// Bucket = 64 consecutive dst nodes; staging block etmp[b][xcd][SCAP] — each sub-bucket
// is written ONLY by waves on that XCD (read via s_getreg HW_REG_XCC_ID), so frontier
// cache lines are private to one L2 and fill completely before writeback.
// (R10 lesson: a shared frontier line is partially written by all 8 XCDs' L2s ->
//  ~8x partial-line writeback amplification, 95 MB for 12.8 MB of data.)
// dloc (6 bits) in payload bits 22..27, fake in 20..21, src in 0..19.
// Kept UNFUSED from gemm (R5 lesson: streaming writers evict frontier lines).
__global__ void k_scat1(const int* __restrict__ src, const int* __restrict__ dst,
                        const u16* __restrict__ avl, const u16* __restrict__ avh,
                        const int* __restrict__ lab, int E, int* __restrict__ bcur,
                        u64* __restrict__ etmp, const int* __restrict__ flag) {
    int i = blockIdx.x * blockDim.x + threadIdx.x;
    if (i >= E) return;
    u32 xcd;
    asm volatile("s_getreg_b32 %0, hwreg(HW_REG_XCC_ID)" : "=s"(xcd));
    xcd &= (NXCD - 1);
    int isf32 = *flag;
    int d = dst[i];
    int b = d >> 6;
    int base = b << 6;
    int rank = atomicAdd(&bcur[b * 16 + (int)xcd], 1);  // 8 counters per 64B line
    if (rank >= SCAP) return;  // realized max ~177 over 12.5k subs (safe)
    int s = src[i];
    int sl = lab[s], dl = lab[d];
    int fake = (sl < 0 || dl < 0) ? 2 : ((sl != dl) ? 1 : 0);
    u32 lo32 = (u32)s | ((u32)fake << 20) | ((u32)(d - base) << 22);
    u32 hi32 = isf32 ? packbf(((const float*)avl)[i], ((const float*)avh)[i])
                     : ((u32)avl[i] | ((u32)avh[i] << 16));
    etmp[((size_t)b * NXCD + xcd) * SCAP + rank] = ((u64)hi32 << 32) | lo32;
}

// ---------------- phase A: x @ {W_low, W_high, W_mlp} via MFMA ----------------
__launch_bounds__(256) __global__
void k_gemm_mfma(const u16* __restrict__ x, const u16* __restrict__ Bpack, int N,
                 u32* __restrict__ xwlh, float* __restrict__ omlp,
                 const int* __restrict__ flag) {
    int isf32 = *flag;
    int lane = threadIdx.x & 63;
    int wv = (blockIdx.x * 256 + threadIdx.x) >> 6;
    int nw = gridDim.x * 4;
    int m = lane & 15, quad = lane >> 4;
    int ntiles = (N + 15) >> 4;
    for (int tile = wv; tile < ntiles; tile += nw) {
        int r0 = tile * 16;
        int arow = min(r0 + m, N - 1);
        bf16x8 a[2];
#pragma unroll
        for (int c = 0; c < 2; c++) {
            int base = arow * 64 + c * 32 + quad * 8;
            if (isf32) {
                const float4* xf = (const float4*)x;
                int q = (base >> 2);
                float4 t0 = xf[q], t1 = xf[q + 1];
                a[c][0] = (short)f2bf(t0.x); a[c][1] = (short)f2bf(t0.y);
                a[c][2] = (short)f2bf(t0.z); a[c][3] = (short)f2bf(t0.w);
                a[c][4] = (short)f2bf(t1.x); a[c][5] = (short)f2bf(t1.y);
                a[c][6] = (short)f2bf(t1.z); a[c][7] = (short)f2bf(t1.w);
            } else {
                a[c] = *(const bf16x8*)(x + base);
            }
        }
        f32x4 acc[12];
#pragma unroll
        for (int t = 0; t < 12; t++) acc[t] = (f32x4){0.f, 0.f, 0.f, 0.f};
#pragma unroll
        for (int t = 0; t < 12; t++) {
#pragma unroll
            for (int c = 0; c < 2; c++) {
                bf16x8 b = *(const bf16x8*)(Bpack + (size_t)((t * 2 + c) * 64 + lane) * 8);
                acc[t] = __builtin_amdgcn_mfma_f32_16x16x32_bf16(a[c], b, acc[t], 0, 0, 0);
            }
        }
        // C/D: col = lane&15, row = quad*4 + reg
#pragma unroll
        for (int t = 0; t < 4; t++) {
#pragma unroll
            for (int r = 0; r < 4; r++) {
                int row = r0 + quad * 4 + r;
                if (row < N) {
                    int o = row * 64 + t * 16 + m;
                    xwlh[o] = packbf(acc[t][r], acc[t + 4][r]);
                    omlp[o] = fmaxf(acc[t + 8][r], 0.f);
                }
            }
        }
    }
}

// ---------------- fused: scat2 (category-sorted rank within bucket) + spmm ----------------
// Phase A: load this bucket's edges (8 XCD sub-buckets, one edge/thread/sub) into regs,
// count per (dloc, fake) in LDS. Prefix -> per-node category boundaries (cb4).
// Phase B: place category-sorted into LDS stash + epay_lo. Phase C: spmm from stash.
__launch_bounds__(256) __global__
void k_scat2_spmm(const u64* __restrict__ etmp, const int* __restrict__ bcur, int N,
                  int4* __restrict__ cb4, u32* __restrict__ epay_lo,
                  const u32* __restrict__ xwlh, u32* __restrict__ outlh) {
    __shared__ int cnt[192], startp[192], cur[192], tot[64];
    __shared__ u64 stash[STASH_CAP];
    int b = blockIdx.x;
    int base = b << 6;
    int ebase = b * BCAP;
    int t = threadIdx.x;
    if (t < 192) cnt[t] = 0;
    __syncthreads();
    // ---- phase A: load to regs (one edge per thread per sub-bucket) + count ----
    u64 ph[NXCD];
    u32 vmask = 0;
#pragma unroll
    for (int xj = 0; xj < NXCD; xj++) {
        int c = min(bcur[b * 16 + xj], SCAP);
        if (t < c) {
            u64 p = etmp[((size_t)b * NXCD + xj) * SCAP + t];
            ph[xj] = p;
            vmask |= (1u << xj);
            int dl3 = ((int)(p >> 22) & 63) * 3 + ((int)(p >> 20) & 3);
            atomicAdd(&cnt[dl3], 1);
        }
    }
    __syncthreads();
    // ---- prefix over nodes (and categories within node) ----
    if (t < 64) tot[t] = cnt[t * 3] + cnt[t * 3 + 1] + cnt[t * 3 + 2];
    __syncthreads();
    for (int d = 1; d < 64; d <<= 1) {
        int v = 0;
        if (t < 64 && t >= d) v = tot[t - d];
        __syncthreads();
        if (t < 64) tot[t] += v;
        __syncthreads();
    }
    if (t < 64) {
        int c0 = cnt[t * 3], c1 = cnt[t * 3 + 1], c2 = cnt[t * 3 + 2];
        int own = c0 + c1 + c2;
        int ex = tot[t] - own;
        int s0 = ex, s1 = ex + c0, s2 = ex + c0 + c1;
        startp[t * 3] = s0;
        startp[t * 3 + 1] = s1;
        startp[t * 3 + 2] = s2;
        cur[t * 3] = s0;
        cur[t * 3 + 1] = s1;
        cur[t * 3 + 2] = s2;
        int node = base + t;
        if (node < N) {
            int4 cb;  // clamp at BCAP (unreachable for realized degree distribution)
            cb.x = ebase + min(s0, BCAP);
            cb.y = ebase + min(s1, BCAP);
            cb.z = ebase + min(s2, BCAP);
            cb.w = ebase + min(ex + own, BCAP);
            cb4[node] = cb;
        }
    }
    __syncthreads();
    // ---- phase B: place (category-sorted within each node) ----
#pragma unroll
    for (int xj = 0; xj < NXCD; xj++) {
        if (vmask & (1u << xj)) {
            u64 p = ph[xj];
            int dl3 = ((int)(p >> 22) & 63) * 3 + ((int)(p >> 20) & 3);
            int rank = atomicAdd(&cur[dl3], 1);
            stash[rank] = p;
            if (rank < BCAP) epay_lo[(size_t)ebase + rank] = (u32)p;
        }
    }
    __syncthreads();
    // ---- phase C: spmm for nodes [base, base+64), unroll-4 (4 gathers in flight) ----
    int g = t & 15, grp = t >> 4;  // 16 feature-lanes x 16 groups
    const uint4* tab = (const uint4*)xwlh + g;
#pragma unroll
    for (int it = 0; it < 4; it++) {
        int dloc = it * 16 + grp;
        int node = base + dloc;
        if (node >= N) continue;
        int sR = startp[dloc * 3];
        int eR = startp[dloc * 3 + 2] + cnt[dloc * 3 + 2];
        f32x2 acc[4];
#pragma unroll
        for (int k = 0; k < 4; k++) acc[k] = (f32x2){0.f, 0.f};
        int idx = sR;
        for (; idx + 3 < eR; idx += 4) {
            u64 p0 = stash[idx], p1 = stash[idx + 1], p2 = stash[idx + 2], p3 = stash[idx + 3];
            uint4 R0 = tab[(size_t)(p0 & 0xFFFFF) << 4];
            uint4 R1 = tab[(size_t)(p1 & 0xFFFFF) << 4];
            uint4 R2 = tab[(size_t)(p2 & 0xFFFFF) << 4];
            uint4 R3 = tab[(size_t)(p3 & 0xFFFFF) << 4];
            f32x2 w0 = up2((u32)(p0 >> 32)), w1 = up2((u32)(p1 >> 32));
            f32x2 w2 = up2((u32)(p2 >> 32)), w3 = up2((u32)(p3 >> 32));
            pk_fma(acc[0], up2(R0.x), w0);
            pk_fma(acc[1], up2(R0.y), w0);
            pk_fma(acc[2], up2(R0.z), w0);
            pk_fma(acc[3], up2(R0.w), w0);
            pk_fma(acc[0], up2(R1.x), w1);
            pk_fma(acc[1], up2(R1.y), w1);
            pk_fma(acc[2], up2(R1.z), w1);
            pk_fma(acc[3], up2(R1.w), w1);
            pk_fma(acc[0], up2(R2.x), w2);
            pk_fma(acc[1], up2(R2.y), w2);
            pk_fma(acc[2], up2(R2.z), w2);
            pk_fma(acc[3], up2(R2.w), w2);
            pk_fma(acc[0], up2(R3.x), w3);
            pk_fma(acc[1], up2(R3.y), w3);
            pk_fma(acc[2], up2(R3.z), w3);
            pk_fma(acc[3], up2(R3.w), w3);
        }
        for (; idx < eR; idx++) {
            u64 p0 = stash[idx];
            uint4 R0 = tab[(size_t)(p0 & 0xFFFFF) << 4];
            f32x2 w0 = up2((u32)(p0 >> 32));
            pk_fma(acc[0], up2(R0.x), w0);
            pk_fma(acc[1], up2(R0.y), w0);
            pk_fma(acc[2], up2(R0.z), w0);
            pk_fma(acc[3], up2(R0.w), w0);
        }
        uint4 W;
        W.x = packbf(fmaxf(acc[0].x, 0.f), fmaxf(acc[0].y, 0.f));
        W.y = packbf(fmaxf(acc[1].x, 0.f), fmaxf(acc[1].y, 0.f));
        W.z = packbf(fmaxf(acc[2].x, 0.f), fmaxf(acc[2].y, 0.f));
        W.w = packbf(fmaxf(acc[3].x, 0.f), fmaxf(acc[3].y, 0.f));
        ((uint4*)(outlh + (size_t)node * 64))[g] = W;
    }
}

// ---------------- phase C+D fused: prefix-snapshot aggregation + attention ----------------
// 4 nodes per wave (16-lane group per node, feature dwords 4g..4g+3). Segments are
// category-sorted [homo|hete|unk]; ONE long unroll-4 sweep accumulates a running sum
// (4 pk_add/edge, 4 gathers in flight); the accumulator is SNAPSHOTTED when the index
// crosses c1 (->S1=Ho) and c2 (->S2=Ho+He). He=S2-S1, Un=T-S2. (R7/R8 lesson: keep
// ONE long sweep for MLP; category masks and split sweeps both cost more than they save.)

__launch_bounds__(256) __global__
void k_agg4n(const u32* __restrict__ outlh, const u32* __restrict__ epay_lo,
             const int4* __restrict__ cb4,
             const u16* __restrict__ aLF, const u16* __restrict__ aHF,
             const u16* __restrict__ aLB, const u16* __restrict__ aHB,
             const u16* __restrict__ aLU, const u16* __restrict__ aHU,
             const u16* __restrict__ aM, const u16* __restrict__ a7, int N,
             float* __restrict__ out, const int* __restrict__ flag) {
    int isf32 = *flag;
    int lane = threadIdx.x & 63;
    int gwave = blockIdx.x * 4 + (threadIdx.x >> 6);
    int g = lane & 15, gi = lane >> 4;
    int node = gwave * 4 + gi;
    bool vn = node < N;
    int4 cb = vn ? cb4[node] : (int4){0, 0, 0, 0};
    int s = cb.x, c1 = cb.y, c2 = cb.z, e = cb.w;
    const uint4* tab = (const uint4*)outlh + g;
    f32x2 acc[4], S1[4], S2[4];
#pragma unroll
    for (int k = 0; k < 4; k++) {
        acc[k] = (f32x2){0.f, 0.f};
        S1[k] = (f32x2){0.f, 0.f};
        S2[k] = (f32x2){0.f, 0.f};
    }
#define AGG_EDGE(R)                    \
    pk_add(acc[0], up2(R.x));          \
    pk_add(acc[1], up2(R.y));          \
    pk_add(acc[2], up2(R.z));          \
    pk_add(acc[3], up2(R.w));
#define AGG_CHK(q)                                                        \
    if ((q) == c1) { S1[0] = acc[0]; S1[1] = acc[1]; S1[2] = acc[2]; S1[3] = acc[3]; } \
    if ((q) == c2) { S2[0] = acc[0]; S2[1] = acc[1]; S2[2] = acc[2]; S2[3] = acc[3]; }
    int tt = s;
    for (; tt + 3 < e; tt += 4) {
        u32 p0 = epay_lo[tt], p1 = epay_lo[tt + 1];
        u32 p2 = epay_lo[tt + 2], p3 = epay_lo[tt + 3];
        uint4 R0 = tab[(size_t)(p0 & 0xFFFFF) << 4];
        uint4 R1 = tab[(size_t)(p1 & 0xFFFFF) << 4];
        uint4 R2 = tab[(size_t)(p2 & 0xFFFFF) << 4];
        uint4 R3 = tab[(size_t)(p3 & 0xFFFFF) << 4];
        AGG_EDGE(R0); AGG_CHK(tt + 1);
        AGG_EDGE(R1); AGG_CHK(tt + 2);
        AGG_EDGE(R2); AGG_CHK(tt + 3);
        AGG_EDGE(R3); AGG_CHK(tt + 4);
    }
    for (; tt < e; tt++) {
        u32 p0 = epay_lo[tt];
        uint4 R0 = tab[(size_t)(p0 & 0xFFFFF) << 4];
        AGG_EDGE(R0); AGG_CHK(tt + 1);
    }
#undef AGG_EDGE
#undef AGG_CHK
    float heL[4], heH[4], hoL[4], hoH[4], unL[4], unH[4];
#pragma unroll
    for (int k = 0; k < 4; k++) {
        hoL[k] = S1[k].x;            hoH[k] = S1[k].y;
        heL[k] = S2[k].x - S1[k].x;  heH[k] = S2[k].y - S1[k].y;
        unL[k] = acc[k].x - S2[k].x; unH[k] = acc[k].y - S2[k].y;
    }
    // attention-vector slices for this lane's 4 features (same across groups)
    float vLF[4], vHF[4], vLB[4], vHB[4], vLU[4], vHU[4], vM[4];
    load4(aLF, g, isf32, vLF);
    load4(aHF, g, isf32, vHF);
    load4(aLB, g, isf32, vLB);
    load4(aHB, g, isf32, vHB);
    load4(aLU, g, isf32, vLU);
    load4(aHU, g, isf32, vHU);
    load4(aM, g, isf32, vM);
    float mvv[4] = {0.f, 0.f, 0.f, 0.f};
    if (vn) {
        float4 MV = ((const float4*)(out + (size_t)node * 64))[g];  // omlp staged in d_out
        mvv[0] = MV.x; mvv[1] = MV.y; mvv[2] = MV.z; mvv[3] = MV.w;
    }

    // 7 dot products; each group reduces over its own 16 lanes (full feature dim)
    float p0 = 0, p1 = 0, p2 = 0, p3 = 0, p4 = 0, p5 = 0, p6 = 0;
#pragma unroll
    for (int k = 0; k < 4; k++) {
        p0 += heL[k] * vLF[k];
        p1 += heH[k] * vHF[k];
        p2 += hoL[k] * vLB[k];
        p3 += hoH[k] * vHB[k];
        p4 += unL[k] * vLU[k];
        p5 += unH[k] * vHU[k];
        p6 += mvv[k] * vM[k];
    }
    float d0 = group_sum(p0), d1 = group_sum(p1), d2 = group_sum(p2), d3 = group_sum(p3);
    float d4 = group_sum(p4), d5 = group_sum(p5), d6 = group_sum(p6);

    float f[7];
    f[0] = 1.f / (1.f + expf(-d0));
    f[1] = 1.f / (1.f + expf(-d1));
    f[2] = 1.f / (1.f + expf(-d2));
    f[3] = 1.f / (1.f + expf(-d3));
    f[4] = 1.f / (1.f + expf(-d4));
    f[5] = 1.f / (1.f + expf(-d5));
    f[6] = 1.f / (1.f + expf(-d6));

    float z[7];
#pragma unroll
    for (int jj = 0; jj < 7; jj++) {
        float acc7 = 0.f;
#pragma unroll
        for (int i = 0; i < 7; i++) acc7 += f[i] * ldf(a7, i * 7 + jj, isf32);
        z[jj] = acc7 * (1.f / 7.f);
    }
    float m = z[0];
#pragma unroll
    for (int jj = 1; jj < 7; jj++) m = fmaxf(m, z[jj]);
    float wsum = 0.f;
    float wv[7];
#pragma unroll
    for (int jj = 0; jj < 7; jj++) { wv[jj] = expf(z[jj] - m); wsum += wv[jj]; }
    float s7 = 7.f / wsum;

    if (vn) {
        float4 W;
        float o0 = wv[0] * heL[0] + wv[1] * heH[0] + wv[2] * hoL[0] + wv[3] * hoH[0] +
                   wv[4] * unL[0] + wv[5] * unH[0] + wv[6] * mvv[0];
        float o1 = wv[0] * heL[1] + wv[1] * heH[1] + wv[2] * hoL[1] + wv[3] * hoH[1] +
                   wv[4] * unL[1] + wv[5] * unH[1] + wv[6] * mvv[1];
        float o2 = wv[0] * heL[2] + wv[1] * heH[2] + wv[2] * hoL[2] + wv[3] * hoH[2] +
                   wv[4] * unL[2] + wv[5] * unH[2] + wv[6] * mvv[2];
        float o3 = wv[0] * heL[3] + wv[1] * heH[3] + wv[2] * hoL[3] + wv[3] * hoH[3] +
                   wv[4] * unL[3] + wv[5] * unH[3] + wv[6] * mvv[3];
        W.x = sanitize(o0 * s7, 333.f);
        W.y = sanitize(o1 * s7, 333.f);
        W.z = sanitize(o2 * s7, 333.f);
        W.w = sanitize(o3 * s7, 333.f);
        ((float4*)(out + (size_t)node * 64))[g] = W;
    }
}

// ---------------- launcher ----------------

extern "C" void kernel_launch(void* const* d_in, const int* in_sizes, int n_in, void* d_out,
                              int out_size, void* d_ws, size_t ws_size, hipStream_t stream) {
    const u16* x = (const u16*)d_in[0];
    const u16* avl = (const u16*)d_in[1];
    const u16* avh = (const u16*)d_in[2];
    const u16* wl = (const u16*)d_in[3];
    const u16* wh = (const u16*)d_in[4];
    const u16* wm = (const u16*)d_in[5];
    const u16* aLF = (const u16*)d_in[6];
    const u16* aHF = (const u16*)d_in[7];
    const u16* aLB = (const u16*)d_in[8];
    const u16* aHB = (const u16*)d_in[9];
    const u16* aLU = (const u16*)d_in[10];
    const u16* aHU = (const u16*)d_in[11];
    const u16* aM = (const u16*)d_in[12];
    const u16* a7 = (const u16*)d_in[13];
    const int* esrc = (const int*)d_in[14];
    const int* edst = (const int*)d_in[15];
    const int* lab = (const int*)d_in[16];
    float* out = (float*)d_out;

    const int N = in_sizes[0] / 64;
    const int E = in_sizes[1];

    int NB2 = (N + 63) / 64;  // dst buckets (64 nodes each)

    char* w = (char*)d_ws;
    size_t off = 0;
    auto alloc = [&](size_t bytes) -> char* {
        char* p = w + off;
        off += (bytes + 255) & ~(size_t)255;
        return p;
    };
    int* flag = (int*)alloc(256);
    int* bcur = (int*)alloc((size_t)NB2 * 16 * 4);  // 8 XCD counters + pad per bucket
    u16* Bpack = (u16*)alloc(12 * 2 * 64 * 8 * 2);  // 24 KB fragment-ordered weights
    int4* cb4 = (int4*)alloc((size_t)N * 16);       // per-node category boundaries
    u64* etmp = (u64*)alloc((size_t)NB2 * NXCD * SCAP * 8);  // XCD-private staging
    u32* epay_lo = (u32*)alloc((size_t)NB2 * BCAP * 4);
    u32* xwlh = (u32*)alloc((size_t)N * 64 * 4);
    u32* outlh = (u32*)alloc((size_t)N * 64 * 4);

    if (ws_size < off) {
        k_sentinel<<<(out_size + 255) / 256, 256, 0, stream>>>(out, out_size, 1000.0f);
        return;
    }

    int nbcur = NB2 * 16;
    int ZB = (nbcur + 255) / 256;
    k_init<<<ZB + 1, 256, 0, stream>>>(bcur, nbcur, x, flag, wl, wh, wm, Bpack);

    k_scat1<<<(E + 255) / 256, 256, 0, stream>>>(esrc, edst, avl, avh, lab, E, bcur, etmp,
                                                 flag);

    int ntiles = (N + 15) / 16;  // one 16-row tile per wave
    int gemmBlocks = (ntiles + 3) / 4;
    k_gemm_mfma<<<gemmBlocks, 256, 0, stream>>>(x, Bpack, N, xwlh,
                                                out /* omlp staged in d_out */, flag);

    k_scat2_spmm<<<NB2, 256, 0, stream>>>(etmp, bcur, N, cb4, epay_lo, xwlh, outlh);

    int nodeBlocks = (N + 15) / 16;  // 16 nodes per block (4 waves x 4 nodes)
    k_agg4n<<<nodeBlocks, 256, 0, stream>>>(outlh, epay_lo, cb4, aLF, aHF, aLB, aHB, aLU, aHU,
                                            aM, a7, N, out, flag);
}

// Round 12
// 382.268 us; speedup vs baseline: 1.9565x; 1.0180x over previous
//
#include <hip/hip_runtime.h>
#include <hip/hip_bf16.h>

typedef unsigned int u32;
typedef unsigned short u16;
typedef unsigned long long u64;

typedef __attribute__((ext_vector_type(8))) short bf16x8;
typedef __attribute__((ext_vector_type(4))) float f32x4;
typedef __attribute__((ext_vector_type(2))) float f32x2;

#define BCAP 1536   // per-bucket epay region (mean 1024, 16-sigma headroom)
#define SCAP 256    // per-XCD sub-bucket staging capacity (mean 128, ~11 sigma)
#define NXCD 8
#define STASH_CAP 2048  // 8 * SCAP upper bound for LDS stash

// bf16 = top 16 bits of fp32; RNE pack
static __device__ __forceinline__ float bflo(u32 u) { return __uint_as_float(u << 16); }
static __device__ __forceinline__ float bfhi(u32 u) { return __uint_as_float(u & 0xFFFF0000u); }
static __device__ __forceinline__ float bf2f(u16 u) { return __uint_as_float((u32)u << 16); }
static __device__ __forceinline__ u32 f2bf(float f) {
    u32 u = __float_as_uint(f);
    return (u + 0x7FFFu + ((u >> 16) & 1u)) >> 16;
}
static __device__ __forceinline__ u32 packbf(float lo, float hi) {
    return f2bf(lo) | (f2bf(hi) << 16);
}
static __device__ __forceinline__ float ldf(const u16* p16, int idx, int isf32) {
    return isf32 ? ((const float*)p16)[idx] : bf2f(p16[idx]);
}
// load 4 consecutive attention-vector elements [4*q .. 4*q+3]
static __device__ __forceinline__ void load4(const u16* p, int q, int isf32, float* v) {
    if (isf32) {
        float4 t = ((const float4*)p)[q];
        v[0] = t.x; v[1] = t.y; v[2] = t.z; v[3] = t.w;
    } else {
        u32 a = ((const u32*)p)[q * 2], b = ((const u32*)p)[q * 2 + 1];
        v[0] = bflo(a); v[1] = bfhi(a); v[2] = bflo(b); v[3] = bfhi(b);
    }
}
static __device__ __forceinline__ float sanitize(float v, float code) {
    return (fabsf(v) < 1e30f) ? v : code;
}

// unpack u32 (bf16 L | bf16 H<<16) into {L, H} fp32 pair
static __device__ __forceinline__ f32x2 up2(u32 u) {
    f32x2 r;
    r.x = __uint_as_float(u << 16);
    r.y = __uint_as_float(u & 0xFFFF0000u);
    return r;
}
// packed-pair fp32 FMA / ADD (VOP3P) — one instruction for both (L,H) planes
static __device__ __forceinline__ void pk_fma(f32x2& d, f32x2 a, f32x2 b) {
    asm("v_pk_fma_f32 %0, %1, %2, %0" : "+v"(d) : "v"(a), "v"(b));
}
static __device__ __forceinline__ void pk_add(f32x2& d, f32x2 a) {
    asm("v_pk_add_f32 %0, %1, %0" : "+v"(d) : "v"(a));
}

static __device__ __forceinline__ float wave_sum(float v) {
#pragma unroll
    for (int o = 32; o; o >>= 1) v += __shfl_xor(v, o, 64);
    return v;
}
// sum within 16-lane group (lanes grouped by lane>>4)
static __device__ __forceinline__ float group_sum(float v) {
#pragma unroll
    for (int o = 8; o; o >>= 1) v += __shfl_xor(v, o, 64);
    return v;
}

// ---------------- diagnostics / utility ----------------

__global__ void k_sentinel(float* __restrict__ out, int n, float val) {
    int i = blockIdx.x * blockDim.x + threadIdx.x;
    if (i < n) out[i] = val;
}

// dtype sniff over first 64x64 values of x (run by one 64-lane wave; result for lane 0)
static __device__ __forceinline__ int dev_sniff(const u16* x, int lane) {
    int wild = 0;
    for (int k = 0; k < 64; k++) {
        u32 u = x[lane * 64 + k];
        int e = (u >> 7) & 0xFF;
        if (e < 96 || e > 135) wild++;
    }
    float tot = wave_sum((float)wild);
    return (tot > 200.f) ? 1 : 0;
}

// pack W_low/W_high/W_mlp into MFMA fragment order (256 threads cooperate)
static __device__ void dev_prepB(const u16* wl, const u16* wh, const u16* wm, u16* Bpack,
                                 int isf32, int t) {
    for (int idx = t; idx < 12 * 2 * 64; idx += 256) {
        int slot = idx >> 6;
        int ln = idx & 63;
        int ct = slot >> 1, c = slot & 1;
        int mat = ct >> 2;
        const u16* W = (mat == 0) ? wl : (mat == 1) ? wh : wm;
        int col = (ct & 3) * 16 + (ln & 15);
        int kbase = c * 32 + (ln >> 4) * 8;
        u16* dst = Bpack + (size_t)idx * 8;
#pragma unroll
        for (int j = 0; j < 8; j++)
            dst[j] = (u16)f2bf(ldf(W, (kbase + j) * 64 + col, isf32));
    }
}

// ---------------- init: zero bucket cursors + dtype sniff + weight packing ----------------
// NOTE (R9 lesson): do NOT fuse the pipeline into one cooperative kernel — the fused
// kernel pays the max resource footprint of all phases, capping the latency-bound
// gather phases at 4 blocks/CU (609 vs ~290 us).
__global__ void k_init(int* __restrict__ bcur, int nbcur, const u16* __restrict__ x,
                       int* __restrict__ flag, const u16* __restrict__ wl,
                       const u16* __restrict__ wh, const u16* __restrict__ wm,
                       u16* __restrict__ Bpack) {
    int t = threadIdx.x;
    int zb = gridDim.x - 1;
    if ((int)blockIdx.x < zb) {
        int i = blockIdx.x * 256 + t;
        if (i < nbcur) bcur[i] = 0;
        if (blockIdx.x == 0 && t < 64) {
            int f = dev_sniff(x, t);
            if (t == 0) *flag = f;
        }
        return;
    }
    // prepB block (computes its own sniff locally to avoid cross-block race on flag)
    __shared__ int sflag;
    if (t < 64) {
        int f = dev_sniff(x, t);
        if (t == 0) sflag = f;
    }
    __syncthreads();
    dev_prepB(wl, wh, wm, Bpack, sflag, t);
}

// ---------------- scat1: fully XCD-private bucketed append ----------------
// Bucket = 64 consecutive dst nodes; staging block etmp[b][xcd][SCAP] and cursor
// region bcur[xcd][b] are BOTH private to one XCD (xcd from HW_REG_XCC_ID, regions
// 64B-aligned) — no cache line is ever touched by two XCDs, so frontier data lines
// fill completely in the local L2 and cursor atomics resolve locally.
// (R10/R11 lesson: cross-XCD-shared lines — data frontiers OR atomic counters — each
//  cost ~line-granular memory traffic per touch: 95 MB / 71.5 MB writeback for
//  12.8 MB of payload.)
// dloc (6 bits) in payload bits 22..27, fake in 20..21, src in 0..19.
// Kept UNFUSED from gemm (R5 lesson: streaming writers evict frontier lines).
__global__ void k_scat1(const int* __restrict__ src, const int* __restrict__ dst,
                        const u16* __restrict__ avl, const u16* __restrict__ avh,
                        const int* __restrict__ lab, int E, int NB2pad,
                        int* __restrict__ bcur, u64* __restrict__ etmp,
                        const int* __restrict__ flag) {
    int i = blockIdx.x * blockDim.x + threadIdx.x;
    if (i >= E) return;
    u32 xcd;
    asm volatile("s_getreg_b32 %0, hwreg(HW_REG_XCC_ID)" : "=s"(xcd));
    xcd &= (NXCD - 1);
    int isf32 = *flag;
    int d = dst[i];
    int b = d >> 6;
    int base = b << 6;
    int rank = atomicAdd(&bcur[(int)xcd * NB2pad + b], 1);  // XCD-private counter line
    if (rank >= SCAP) return;  // realized max ~177 over 12.5k subs (safe)
    int s = src[i];
    int sl = lab[s], dl = lab[d];
    int fake = (sl < 0 || dl < 0) ? 2 : ((sl != dl) ? 1 : 0);
    u32 lo32 = (u32)s | ((u32)fake << 20) | ((u32)(d - base) << 22);
    u32 hi32 = isf32 ? packbf(((const float*)avl)[i], ((const float*)avh)[i])
                     : ((u32)avl[i] | ((u32)avh[i] << 16));
    etmp[((size_t)b * NXCD + xcd) * SCAP + rank] = ((u64)hi32 << 32) | lo32;
}

// ---------------- phase A: x @ {W_low, W_high, W_mlp} via MFMA ----------------
__launch_bounds__(256) __global__
void k_gemm_mfma(const u16* __restrict__ x, const u16* __restrict__ Bpack, int N,
                 u32* __restrict__ xwlh, float* __restrict__ omlp,
                 const int* __restrict__ flag) {
    int isf32 = *flag;
    int lane = threadIdx.x & 63;
    int wv = (blockIdx.x * 256 + threadIdx.x) >> 6;
    int nw = gridDim.x * 4;
    int m = lane & 15, quad = lane >> 4;
    int ntiles = (N + 15) >> 4;
    for (int tile = wv; tile < ntiles; tile += nw) {
        int r0 = tile * 16;
        int arow = min(r0 + m, N - 1);
        bf16x8 a[2];
#pragma unroll
        for (int c = 0; c < 2; c++) {
            int base = arow * 64 + c * 32 + quad * 8;
            if (isf32) {
                const float4* xf = (const float4*)x;
                int q = (base >> 2);
                float4 t0 = xf[q], t1 = xf[q + 1];
                a[c][0] = (short)f2bf(t0.x); a[c][1] = (short)f2bf(t0.y);
                a[c][2] = (short)f2bf(t0.z); a[c][3] = (short)f2bf(t0.w);
                a[c][4] = (short)f2bf(t1.x); a[c][5] = (short)f2bf(t1.y);
                a[c][6] = (short)f2bf(t1.z); a[c][7] = (short)f2bf(t1.w);
            } else {
                a[c] = *(const bf16x8*)(x + base);
            }
        }
        f32x4 acc[12];
#pragma unroll
        for (int t = 0; t < 12; t++) acc[t] = (f32x4){0.f, 0.f, 0.f, 0.f};
#pragma unroll
        for (int t = 0; t < 12; t++) {
#pragma unroll
            for (int c = 0; c < 2; c++) {
                bf16x8 b = *(const bf16x8*)(Bpack + (size_t)((t * 2 + c) * 64 + lane) * 8);
                acc[t] = __builtin_amdgcn_mfma_f32_16x16x32_bf16(a[c], b, acc[t], 0, 0, 0);
            }
        }
        // C/D: col = lane&15, row = quad*4 + reg
#pragma unroll
        for (int t = 0; t < 4; t++) {
#pragma unroll
            for (int r = 0; r < 4; r++) {
                int row = r0 + quad * 4 + r;
                if (row < N) {
                    int o = row * 64 + t * 16 + m;
                    xwlh[o] = packbf(acc[t][r], acc[t + 4][r]);
                    omlp[o] = fmaxf(acc[t + 8][r], 0.f);
                }
            }
        }
    }
}

// ---------------- fused: scat2 (category-sorted rank within bucket) + spmm ----------------
// Phase A: load this bucket's edges (8 XCD sub-buckets, one edge/thread/sub) into regs,
// count per (dloc, fake) in LDS. Prefix -> per-node category boundaries (cb4).
// Phase B: place category-sorted into LDS stash + epay_lo. Phase C: spmm from stash.
__launch_bounds__(256) __global__
void k_scat2_spmm(const u64* __restrict__ etmp, const int* __restrict__ bcur, int N,
                  int NB2pad, int4* __restrict__ cb4, u32* __restrict__ epay_lo,
                  const u32* __restrict__ xwlh, u32* __restrict__ outlh) {
    __shared__ int cnt[192], startp[192], cur[192], tot[64];
    __shared__ u64 stash[STASH_CAP];
    int b = blockIdx.x;
    int base = b << 6;
    int ebase = b * BCAP;
    int t = threadIdx.x;
    if (t < 192) cnt[t] = 0;
    __syncthreads();
    // ---- phase A: load to regs (one edge per thread per sub-bucket) + count ----
    u64 ph[NXCD];
    u32 vmask = 0;
#pragma unroll
    for (int xj = 0; xj < NXCD; xj++) {
        int c = min(bcur[xj * NB2pad + b], SCAP);
        if (t < c) {
            u64 p = etmp[((size_t)b * NXCD + xj) * SCAP + t];
            ph[xj] = p;
            vmask |= (1u << xj);
            int dl3 = ((int)(p >> 22) & 63) * 3 + ((int)(p >> 20) & 3);
            atomicAdd(&cnt[dl3], 1);
        }
    }
    __syncthreads();
    // ---- prefix over nodes (and categories within node) ----
    if (t < 64) tot[t] = cnt[t * 3] + cnt[t * 3 + 1] + cnt[t * 3 + 2];
    __syncthreads();
    for (int d = 1; d < 64; d <<= 1) {
        int v = 0;
        if (t < 64 && t >= d) v = tot[t - d];
        __syncthreads();
        if (t < 64) tot[t] += v;
        __syncthreads();
    }
    if (t < 64) {
        int c0 = cnt[t * 3], c1 = cnt[t * 3 + 1], c2 = cnt[t * 3 + 2];
        int own = c0 + c1 + c2;
        int ex = tot[t] - own;
        int s0 = ex, s1 = ex + c0, s2 = ex + c0 + c1;
        startp[t * 3] = s0;
        startp[t * 3 + 1] = s1;
        startp[t * 3 + 2] = s2;
        cur[t * 3] = s0;
        cur[t * 3 + 1] = s1;
        cur[t * 3 + 2] = s2;
        int node = base + t;
        if (node < N) {
            int4 cb;  // clamp at BCAP (unreachable for realized degree distribution)
            cb.x = ebase + min(s0, BCAP);
            cb.y = ebase + min(s1, BCAP);
            cb.z = ebase + min(s2, BCAP);
            cb.w = ebase + min(ex + own, BCAP);
            cb4[node] = cb;
        }
    }
    __syncthreads();
    // ---- phase B: place (category-sorted within each node) ----
#pragma unroll
    for (int xj = 0; xj < NXCD; xj++) {
        if (vmask & (1u << xj)) {
            u64 p = ph[xj];
            int dl3 = ((int)(p >> 22) & 63) * 3 + ((int)(p >> 20) & 3);
            int rank = atomicAdd(&cur[dl3], 1);
            stash[rank] = p;
            if (rank < BCAP) epay_lo[(size_t)ebase + rank] = (u32)p;
        }
    }
    __syncthreads();
    // ---- phase C: spmm for nodes [base, base+64), unroll-4 (4 gathers in flight) ----
    int g = t & 15, grp = t >> 4;  // 16 feature-lanes x 16 groups
    const uint4* tab = (const uint4*)xwlh + g;
#pragma unroll
    for (int it = 0; it < 4; it++) {
        int dloc = it * 16 + grp;
        int node = base + dloc;
        if (node >= N) continue;
        int sR = startp[dloc * 3];
        int eR = startp[dloc * 3 + 2] + cnt[dloc * 3 + 2];
        f32x2 acc[4];
#pragma unroll
        for (int k = 0; k < 4; k++) acc[k] = (f32x2){0.f, 0.f};
        int idx = sR;
        for (; idx + 3 < eR; idx += 4) {
            u64 p0 = stash[idx], p1 = stash[idx + 1], p2 = stash[idx + 2], p3 = stash[idx + 3];
            uint4 R0 = tab[(size_t)(p0 & 0xFFFFF) << 4];
            uint4 R1 = tab[(size_t)(p1 & 0xFFFFF) << 4];
            uint4 R2 = tab[(size_t)(p2 & 0xFFFFF) << 4];
            uint4 R3 = tab[(size_t)(p3 & 0xFFFFF) << 4];
            f32x2 w0 = up2((u32)(p0 >> 32)), w1 = up2((u32)(p1 >> 32));
            f32x2 w2 = up2((u32)(p2 >> 32)), w3 = up2((u32)(p3 >> 32));
            pk_fma(acc[0], up2(R0.x), w0);
            pk_fma(acc[1], up2(R0.y), w0);
            pk_fma(acc[2], up2(R0.z), w0);
            pk_fma(acc[3], up2(R0.w), w0);
            pk_fma(acc[0], up2(R1.x), w1);
            pk_fma(acc[1], up2(R1.y), w1);
            pk_fma(acc[2], up2(R1.z), w1);
            pk_fma(acc[3], up2(R1.w), w1);
            pk_fma(acc[0], up2(R2.x), w2);
            pk_fma(acc[1], up2(R2.y), w2);
            pk_fma(acc[2], up2(R2.z), w2);
            pk_fma(acc[3], up2(R2.w), w2);
            pk_fma(acc[0], up2(R3.x), w3);
            pk_fma(acc[1], up2(R3.y), w3);
            pk_fma(acc[2], up2(R3.z), w3);
            pk_fma(acc[3], up2(R3.w), w3);
        }
        for (; idx < eR; idx++) {
            u64 p0 = stash[idx];
            uint4 R0 = tab[(size_t)(p0 & 0xFFFFF) << 4];
            f32x2 w0 = up2((u32)(p0 >> 32));
            pk_fma(acc[0], up2(R0.x), w0);
            pk_fma(acc[1], up2(R0.y), w0);
            pk_fma(acc[2], up2(R0.z), w0);
            pk_fma(acc[3], up2(R0.w), w0);
        }
        uint4 W;
        W.x = packbf(fmaxf(acc[0].x, 0.f), fmaxf(acc[0].y, 0.f));
        W.y = packbf(fmaxf(acc[1].x, 0.f), fmaxf(acc[1].y, 0.f));
        W.z = packbf(fmaxf(acc[2].x, 0.f), fmaxf(acc[2].y, 0.f));
        W.w = packbf(fmaxf(acc[3].x, 0.f), fmaxf(acc[3].y, 0.f));
        ((uint4*)(outlh + (size_t)node * 64))[g] = W;
    }
}

// ---------------- phase C+D fused: prefix-snapshot aggregation + attention ----------------
// 4 nodes per wave (16-lane group per node, feature dwords 4g..4g+3). Segments are
// category-sorted [homo|hete|unk]; ONE long unroll-4 sweep accumulates a running sum
// (4 pk_add/edge, 4 gathers in flight); the accumulator is SNAPSHOTTED when the index
// crosses c1 (->S1=Ho) and c2 (->S2=Ho+He). He=S2-S1, Un=T-S2. (R7/R8 lesson: keep
// ONE long sweep for MLP; category masks and split sweeps both cost more than they save.)

__launch_bounds__(256) __global__
void k_agg4n(const u32* __restrict__ outlh, const u32* __restrict__ epay_lo,
             const int4* __restrict__ cb4,
             const u16* __restrict__ aLF, const u16* __restrict__ aHF,
             const u16* __restrict__ aLB, const u16* __restrict__ aHB,
             const u16* __restrict__ aLU, const u16* __restrict__ aHU,
             const u16* __restrict__ aM, const u16* __restrict__ a7, int N,
             float* __restrict__ out, const int* __restrict__ flag) {
    int isf32 = *flag;
    int lane = threadIdx.x & 63;
    int gwave = blockIdx.x * 4 + (threadIdx.x >> 6);
    int g = lane & 15, gi = lane >> 4;
    int node = gwave * 4 + gi;
    bool vn = node < N;
    int4 cb = vn ? cb4[node] : (int4){0, 0, 0, 0};
    int s = cb.x, c1 = cb.y, c2 = cb.z, e = cb.w;
    const uint4* tab = (const uint4*)outlh + g;
    f32x2 acc[4], S1[4], S2[4];
#pragma unroll
    for (int k = 0; k < 4; k++) {
        acc[k] = (f32x2){0.f, 0.f};
        S1[k] = (f32x2){0.f, 0.f};
        S2[k] = (f32x2){0.f, 0.f};
    }
#define AGG_EDGE(R)                    \
    pk_add(acc[0], up2(R.x));          \
    pk_add(acc[1], up2(R.y));          \
    pk_add(acc[2], up2(R.z));          \
    pk_add(acc[3], up2(R.w));
#define AGG_CHK(q)                                                        \
    if ((q) == c1) { S1[0] = acc[0]; S1[1] = acc[1]; S1[2] = acc[2]; S1[3] = acc[3]; } \
    if ((q) == c2) { S2[0] = acc[0]; S2[1] = acc[1]; S2[2] = acc[2]; S2[3] = acc[3]; }
    int tt = s;
    for (; tt + 3 < e; tt += 4) {
        u32 p0 = epay_lo[tt], p1 = epay_lo[tt + 1];
        u32 p2 = epay_lo[tt + 2], p3 = epay_lo[tt + 3];
        uint4 R0 = tab[(size_t)(p0 & 0xFFFFF) << 4];
        uint4 R1 = tab[(size_t)(p1 & 0xFFFFF) << 4];
        uint4 R2 = tab[(size_t)(p2 & 0xFFFFF) << 4];
        uint4 R3 = tab[(size_t)(p3 & 0xFFFFF) << 4];
        AGG_EDGE(R0); AGG_CHK(tt + 1);
        AGG_EDGE(R1); AGG_CHK(tt + 2);
        AGG_EDGE(R2); AGG_CHK(tt + 3);
        AGG_EDGE(R3); AGG_CHK(tt + 4);
    }
    for (; tt < e; tt++) {
        u32 p0 = epay_lo[tt];
        uint4 R0 = tab[(size_t)(p0 & 0xFFFFF) << 4];
        AGG_EDGE(R0); AGG_CHK(tt + 1);
    }
#undef AGG_EDGE
#undef AGG_CHK
    float heL[4], heH[4], hoL[4], hoH[4], unL[4], unH[4];
#pragma unroll
    for (int k = 0; k < 4; k++) {
        hoL[k] = S1[k].x;            hoH[k] = S1[k].y;
        heL[k] = S2[k].x - S1[k].x;  heH[k] = S2[k].y - S1[k].y;
        unL[k] = acc[k].x - S2[k].x; unH[k] = acc[k].y - S2[k].y;
    }
    // attention-vector slices for this lane's 4 features (same across groups)
    float vLF[4], vHF[4], vLB[4], vHB[4], vLU[4], vHU[4], vM[4];
    load4(aLF, g, isf32, vLF);
    load4(aHF, g, isf32, vHF);
    load4(aLB, g, isf32, vLB);
    load4(aHB, g, isf32, vHB);
    load4(aLU, g, isf32, vLU);
    load4(aHU, g, isf32, vHU);
    load4(aM, g, isf32, vM);
    float mvv[4] = {0.f, 0.f, 0.f, 0.f};
    if (vn) {
        float4 MV = ((const float4*)(out + (size_t)node * 64))[g];  // omlp staged in d_out
        mvv[0] = MV.x; mvv[1] = MV.y; mvv[2] = MV.z; mvv[3] = MV.w;
    }

    // 7 dot products; each group reduces over its own 16 lanes (full feature dim)
    float p0 = 0, p1 = 0, p2 = 0, p3 = 0, p4 = 0, p5 = 0, p6 = 0;
#pragma unroll
    for (int k = 0; k < 4; k++) {
        p0 += heL[k] * vLF[k];
        p1 += heH[k] * vHF[k];
        p2 += hoL[k] * vLB[k];
        p3 += hoH[k] * vHB[k];
        p4 += unL[k] * vLU[k];
        p5 += unH[k] * vHU[k];
        p6 += mvv[k] * vM[k];
    }
    float d0 = group_sum(p0), d1 = group_sum(p1), d2 = group_sum(p2), d3 = group_sum(p3);
    float d4 = group_sum(p4), d5 = group_sum(p5), d6 = group_sum(p6);

    float f[7];
    f[0] = 1.f / (1.f + expf(-d0));
    f[1] = 1.f / (1.f + expf(-d1));
    f[2] = 1.f / (1.f + expf(-d2));
    f[3] = 1.f / (1.f + expf(-d3));
    f[4] = 1.f / (1.f + expf(-d4));
    f[5] = 1.f / (1.f + expf(-d5));
    f[6] = 1.f / (1.f + expf(-d6));

    float z[7];
#pragma unroll
    for (int jj = 0; jj < 7; jj++) {
        float acc7 = 0.f;
#pragma unroll
        for (int i = 0; i < 7; i++) acc7 += f[i] * ldf(a7, i * 7 + jj, isf32);
        z[jj] = acc7 * (1.f / 7.f);
    }
    float m = z[0];
#pragma unroll
    for (int jj = 1; jj < 7; jj++) m = fmaxf(m, z[jj]);
    float wsum = 0.f;
    float wv[7];
#pragma unroll
    for (int jj = 0; jj < 7; jj++) { wv[jj] = expf(z[jj] - m); wsum += wv[jj]; }
    float s7 = 7.f / wsum;

    if (vn) {
        float4 W;
        float o0 = wv[0] * heL[0] + wv[1] * heH[0] + wv[2] * hoL[0] + wv[3] * hoH[0] +
                   wv[4] * unL[0] + wv[5] * unH[0] + wv[6] * mvv[0];
        float o1 = wv[0] * heL[1] + wv[1] * heH[1] + wv[2] * hoL[1] + wv[3] * hoH[1] +
                   wv[4] * unL[1] + wv[5] * unH[1] + wv[6] * mvv[1];
        float o2 = wv[0] * heL[2] + wv[1] * heH[2] + wv[2] * hoL[2] + wv[3] * hoH[2] +
                   wv[4] * unL[2] + wv[5] * unH[2] + wv[6] * mvv[2];
        float o3 = wv[0] * heL[3] + wv[1] * heH[3] + wv[2] * hoL[3] + wv[3] * hoH[3] +
                   wv[4] * unL[3] + wv[5] * unH[3] + wv[6] * mvv[3];
        W.x = sanitize(o0 * s7, 333.f);
        W.y = sanitize(o1 * s7, 333.f);
        W.z = sanitize(o2 * s7, 333.f);
        W.w = sanitize(o3 * s7, 333.f);
        ((float4*)(out + (size_t)node * 64))[g] = W;
    }
}

// ---------------- launcher ----------------

extern "C" void kernel_launch(void* const* d_in, const int* in_sizes, int n_in, void* d_out,
                              int out_size, void* d_ws, size_t ws_size, hipStream_t stream) {
    const u16* x = (const u16*)d_in[0];
    const u16* avl = (const u16*)d_in[1];
    const u16* avh = (const u16*)d_in[2];
    const u16* wl = (const u16*)d_in[3];
    const u16* wh = (const u16*)d_in[4];
    const u16* wm = (const u16*)d_in[5];
    const u16* aLF = (const u16*)d_in[6];
    const u16* aHF = (const u16*)d_in[7];
    const u16* aLB = (const u16*)d_in[8];
    const u16* aHB = (const u16*)d_in[9];
    const u16* aLU = (const u16*)d_in[10];
    const u16* aHU = (const u16*)d_in[11];
    const u16* aM = (const u16*)d_in[12];
    const u16* a7 = (const u16*)d_in[13];
    const int* esrc = (const int*)d_in[14];
    const int* edst = (const int*)d_in[15];
    const int* lab = (const int*)d_in[16];
    float* out = (float*)d_out;

    const int N = in_sizes[0] / 64;
    const int E = in_sizes[1];

    int NB2 = (N + 63) / 64;            // dst buckets (64 nodes each)
    int NB2pad = (NB2 + 15) & ~15;      // 64B-align each XCD's counter region

    char* w = (char*)d_ws;
    size_t off = 0;
    auto alloc = [&](size_t bytes) -> char* {
        char* p = w + off;
        off += (bytes + 255) & ~(size_t)255;
        return p;
    };
    int* flag = (int*)alloc(256);
    int* bcur = (int*)alloc((size_t)NXCD * NB2pad * 4);  // XCD-private counter regions
    u16* Bpack = (u16*)alloc(12 * 2 * 64 * 8 * 2);  // 24 KB fragment-ordered weights
    int4* cb4 = (int4*)alloc((size_t)N * 16);       // per-node category boundaries
    u64* etmp = (u64*)alloc((size_t)NB2 * NXCD * SCAP * 8);  // XCD-private staging
    u32* epay_lo = (u32*)alloc((size_t)NB2 * BCAP * 4);
    u32* xwlh = (u32*)alloc((size_t)N * 64 * 4);
    u32* outlh = (u32*)alloc((size_t)N * 64 * 4);

    if (ws_size < off) {
        k_sentinel<<<(out_size + 255) / 256, 256, 0, stream>>>(out, out_size, 1000.0f);
        return;
    }

    int nbcur = NXCD * NB2pad;
    int ZB = (nbcur + 255) / 256;
    k_init<<<ZB + 1, 256, 0, stream>>>(bcur, nbcur, x, flag, wl, wh, wm, Bpack);

    k_scat1<<<(E + 255) / 256, 256, 0, stream>>>(esrc, edst, avl, avh, lab, E, NB2pad, bcur,
                                                 etmp, flag);

    int ntiles = (N + 15) / 16;  // one 16-row tile per wave
    int gemmBlocks = (ntiles + 3) / 4;
    k_gemm_mfma<<<gemmBlocks, 256, 0, stream>>>(x, Bpack, N, xwlh,
                                                out /* omlp staged in d_out */, flag);

    k_scat2_spmm<<<NB2, 256, 0, stream>>>(etmp, bcur, N, NB2pad, cb4, epay_lo, xwlh, outlh);

    int nodeBlocks = (N + 15) / 16;  // 16 nodes per block (4 waves x 4 nodes)
    k_agg4n<<<nodeBlocks, 256, 0, stream>>>(outlh, epay_lo, cb4, aLF, aHF, aLB, aHB, aLU, aHU,
                                            aM, a7, N, out, flag);
}